// Round 4
// baseline (720.981 us; speedup 1.0000x reference)
//
#include <hip/hip_runtime.h>
#include <hip/hip_bf16.h>

typedef unsigned long long u64;

#define KNMS 1000      // MAX_BOX_PRE_NMS (hardcoded in reference)
#define KP   1024      // padded stride for per-pair arrays
#define CAP  4096      // candidate capacity per pair
#define NBIN 8192      // radix-select histogram bins (score bits >> 18)
#define SLC  8         // A-dimension splits for hist/compact
#define FBN  8192      // final per-batch sort size (>= C*mb)
#define IOU_THR 0.5f

#define NEGINF __uint_as_float(0xFF800000u)

// ---------------------------------------------------------------------------
// helpers
// ---------------------------------------------------------------------------

// Find the histogram bin containing rank `rank` counting from the TOP.
__device__ __forceinline__ void find_cutoff(unsigned int* hist, int nbins,
    unsigned int* csum, int nthreads, int tid, unsigned int rank,
    unsigned int* s_bin, unsigned int* s_gt, unsigned int* s_total, int* s_all) {
  int chunk = nbins / nthreads;
  unsigned int cs = 0;
  int base = tid * chunk;
  for (int q = 0; q < chunk; q++) cs += hist[base + q];
  csum[tid] = cs;
  __syncthreads();
  if (tid == 0) {
    unsigned int total = 0;
    for (int ch = 0; ch < nthreads; ch++) total += csum[ch];
    *s_total = total;
    if (total <= rank) { *s_bin = 0u; *s_gt = 0u; *s_all = 1; }
    else {
      unsigned int acc = 0; int ch = nthreads - 1;
      while (acc + csum[ch] < rank) { acc += csum[ch]; ch--; }
      int bin = ch * chunk + chunk - 1;
      while (acc + hist[bin] < rank) { acc += hist[bin]; bin--; }
      *s_bin = (unsigned)bin; *s_gt = acc; *s_all = 0;
    }
  }
  __syncthreads();
}

// In-LDS bitonic sort, descending, 64-bit keys.
template<int N, int NT>
__device__ __forceinline__ void bitonic_desc(u64* a, int tid) {
  for (int k = 2; k <= N; k <<= 1) {
    for (int j = k >> 1; j > 0; j >>= 1) {
      for (int t = tid; t < N; t += NT) {
        int ixj = t ^ j;
        if (ixj > t) {
          u64 x = a[t], y = a[ixj];
          if (((t & k) == 0) ? (x < y) : (x > y)) { a[t] = y; a[ixj] = x; }
        }
      }
      __syncthreads();
    }
  }
}

// Bit-exact greedy-NMS predicate vs reference:
// fl(inter/uni) > 0.5  <=>  2*inter > uni*(1+2^-24), exact in f64
// (24-bit x 25-bit mantissas fit 53 bits; midpoint ties round to even 0.5;
//  inter=uni=0 -> NaN -> false on both sides; uni<0 impossible).
__device__ __forceinline__ bool iou_gt(float4 bi, float ai, float4 bj, float aj) {
  float ltx = fmaxf(bi.x, bj.x), lty = fmaxf(bi.y, bj.y);
  float rbx = fminf(bi.z, bj.z), rby = fminf(bi.w, bj.w);
  float ww = fmaxf(rbx - ltx, 0.f), hh = fmaxf(rby - lty, 0.f);
  float inter = ww * hh;
  float uni = (ai + aj) - inter;
  return ((double)inter * 2.0 > (double)uni * (1.0 + 0x1p-24));
}

// ---------------------------------------------------------------------------
// kernel 1: transpose classification [B,A,C] -> [B,C,A]  (C <= 127)
// ---------------------------------------------------------------------------
__global__ __launch_bounds__(256) void k_transpose(const float* __restrict__ src0,
    float* __restrict__ dst0, int A, int C) {
  __shared__ float tile[64 * 129];
  int b = blockIdx.y;
  int a0 = blockIdx.x * 64;
  const float* src = src0 + (size_t)b * A * C;
  float* dst = dst0 + (size_t)b * A * C;
  int st = C + 1;
  for (int idx = threadIdx.x; idx < 64 * C; idx += 256) {
    int al = idx / C, c = idx - al * C;
    int a = a0 + al;
    tile[al * st + c] = (a < A) ? src[(size_t)a * C + c] : 0.f;
  }
  __syncthreads();
  for (int idx = threadIdx.x; idx < 64 * C; idx += 256) {
    int c = idx >> 6, al = idx & 63;
    int a = a0 + al;
    if (a < A) dst[(size_t)c * A + a] = tile[al * st + c];
  }
}

// ---------------------------------------------------------------------------
// kernel 2a: per (pair, slice): LDS histogram of score bits>>18, merged to
// global hist via non-returning atomics (only ~32 nonzero bins/block).
// ---------------------------------------------------------------------------
__global__ __launch_bounds__(256) void k_hist(const float* __restrict__ cls,
    int transposed, const float* __restrict__ thr_p,
    unsigned int* __restrict__ ghist, int A, int C) {
  int pair = blockIdx.x, s = blockIdx.y, tid = threadIdx.x;
  int b = pair / C, c = pair - b * C;
  const float* col; int str;
  if (transposed) { col = cls + (size_t)pair * A; str = 1; }
  else            { col = cls + (size_t)b * A * C + c; str = C; }
  float thr = *thr_p;
  __shared__ unsigned int lh[NBIN];
  for (int i = tid; i < NBIN; i += 256) lh[i] = 0u;
  __syncthreads();
  bool vec = (str == 1) && ((A & 3) == 0);
  if (vec) {
    const float4* col4 = (const float4*)col;
    int A4 = A >> 2;
    int n4 = (A4 + SLC - 1) / SLC, i0 = s * n4, i1 = min(A4, i0 + n4);
    for (int i = i0 + tid; i < i1; i += 256) {
      float4 v = col4[i];
      float vv[4] = {v.x, v.y, v.z, v.w};
#pragma unroll
      for (int q = 0; q < 4; q++)
        if (vv[q] > thr) atomicAdd(&lh[__float_as_uint(vv[q]) >> 18], 1u);
    }
  } else {
    int nE = (A + SLC - 1) / SLC, a0 = s * nE, a1 = min(A, a0 + nE);
    for (int a = a0 + tid; a < a1; a += 256) {
      float sv = col[(size_t)a * str];
      if (sv > thr) atomicAdd(&lh[__float_as_uint(sv) >> 18], 1u);
    }
  }
  __syncthreads();
  unsigned int* gh = ghist + (size_t)pair * NBIN;
  for (int i = tid; i < NBIN; i += 256) {
    unsigned v = lh[i];
    if (v) atomicAdd(&gh[i], v);
  }
}

// ---------------------------------------------------------------------------
// kernel 2b: per pair: find cutoff bin for rank KNMS. cut=0 means take-all.
// Margin: bin width 2^-18 -> boundary-bin count ~1.6K for this workload;
// takers <= ~2.6K << CAP=4096.
// ---------------------------------------------------------------------------
__global__ __launch_bounds__(512) void k_cutoff(const unsigned int* __restrict__ ghist,
    unsigned int* __restrict__ cut) {
  int pair = blockIdx.x, tid = threadIdx.x;
  __shared__ unsigned int lh[NBIN];
  __shared__ unsigned int csum[512];
  __shared__ unsigned int s_b1, s_gt, s_tot;
  __shared__ int s_all;
  const unsigned int* gh = ghist + (size_t)pair * NBIN;
  for (int i = tid; i < NBIN; i += 512) lh[i] = gh[i];
  __syncthreads();
  find_cutoff(lh, NBIN, csum, 512, tid, KNMS, &s_b1, &s_gt, &s_tot, &s_all);
  if (tid == 0) cut[pair] = s_all ? 0u : s_b1;
}

// ---------------------------------------------------------------------------
// kernel 2c: per (pair, slice): compact keys with bin >= cut. LDS staging,
// one returning global atomic per BLOCK, bulk coalesced dump.
// key = (score_bits << 32) | ~anchor_index (stable: low index wins ties)
// ---------------------------------------------------------------------------
__global__ __launch_bounds__(256) void k_compact(const float* __restrict__ cls,
    int transposed, const float* __restrict__ thr_p,
    const unsigned int* __restrict__ cut, int* __restrict__ gcnt,
    u64* __restrict__ gcand, int A, int C) {
  int pair = blockIdx.x, s = blockIdx.y, tid = threadIdx.x;
  int b = pair / C, c = pair - b * C;
  const float* col; int str;
  if (transposed) { col = cls + (size_t)pair * A; str = 1; }
  else            { col = cls + (size_t)b * A * C + c; str = C; }
  float thr = *thr_p;
  unsigned b1 = cut[pair];

  __shared__ u64 sbuf[CAP];
  __shared__ int s_n, s_base;
  if (tid == 0) s_n = 0;
  __syncthreads();

  int lane = tid & 63;
  auto stage = [&](u64 key, bool take) {
    u64 m = __ballot(take);
    if (!m) return;
    int ldr = __ffsll((long long)m) - 1;
    int base = 0;
    if (lane == ldr) base = atomicAdd(&s_n, (int)__popcll(m));
    base = __shfl(base, ldr);
    if (take) {
      int pos = base + (int)__popcll(m & ((1ull << lane) - 1ull));
      if (pos < CAP) sbuf[pos] = key;
    }
  };

  bool vec = (str == 1) && ((A & 3) == 0);
  if (vec) {
    const float4* col4 = (const float4*)col;
    int A4 = A >> 2;
    int n4 = (A4 + SLC - 1) / SLC, i0 = s * n4, i1 = min(A4, i0 + n4);
    for (int i = i0 + tid; i < i1; i += 256) {
      float4 v = col4[i];
      float vv[4] = {v.x, v.y, v.z, v.w};
#pragma unroll
      for (int q = 0; q < 4; q++) {
        float sv = vv[q];
        unsigned bits = __float_as_uint(sv);
        bool take = (sv > thr) && ((bits >> 18) >= b1);
        u64 key = ((u64)bits << 32) | (unsigned)(~(unsigned)(i * 4 + q));
        stage(key, take);
      }
    }
  } else {
    int nE = (A + SLC - 1) / SLC, a0 = s * nE, a1 = min(A, a0 + nE);
    for (int a = a0 + tid; a < a1; a += 256) {
      float sv = col[(size_t)a * str];
      unsigned bits = __float_as_uint(sv);
      bool take = (sv > thr) && ((bits >> 18) >= b1);
      u64 key = ((u64)bits << 32) | (unsigned)(~(unsigned)a);
      stage(key, take);
    }
  }
  __syncthreads();
  int n = s_n < CAP ? s_n : CAP;
  if (tid == 0) s_base = atomicAdd(&gcnt[pair], s_n);  // true total (unclamped)
  __syncthreads();
  int base = s_base;
  u64* dst = gcand + (size_t)pair * CAP;
  for (int t = tid; t < n; t += 256) {
    int pos = base + t;
    if (pos < CAP) dst[pos] = sbuf[t];
  }
}

// ---------------------------------------------------------------------------
// kernel 2d: per pair: sort candidates desc, gather boxes, write sorted arrays
// ---------------------------------------------------------------------------
__global__ __launch_bounds__(1024) void k_sortpairs(const u64* __restrict__ gcand,
    const int* __restrict__ gcnt, const float* __restrict__ tanch,
    float* __restrict__ scores_s, float* __restrict__ boxes_s,
    float* __restrict__ area_s, int* __restrict__ cnt_s, int A, int C) {
  int pair = blockIdx.x, tid = threadIdx.x;
  int b = pair / C;
  __shared__ u64 cand[CAP];
  int nc = gcnt[pair];
  int n = nc < CAP ? nc : CAP;
  for (int t = tid; t < CAP; t += 1024)
    cand[t] = (t < n) ? gcand[(size_t)pair * CAP + t] : 0ull;
  __syncthreads();
  bitonic_desc<CAP, 1024>(cand, tid);
  int n_valid = nc < KNMS ? nc : KNMS;
  for (int k = tid; k < KNMS; k += 1024) {
    u64 key = cand[k];
    float sc; float4 bx; float ar;
    if (k < n_valid && key != 0ull) {
      sc = __uint_as_float((unsigned)(key >> 32));
      unsigned a = ~(unsigned)key;
      bx = ((const float4*)tanch)[(size_t)b * A + a];
      ar = (bx.z - bx.x) * (bx.w - bx.y);
    } else {
      sc = NEGINF; bx = make_float4(0.f, 0.f, 0.f, 0.f); ar = 0.f;
    }
    scores_s[(size_t)pair * KP + k] = sc;
    ((float4*)boxes_s)[(size_t)pair * KP + k] = bx;
    area_s[(size_t)pair * KP + k] = ar;
  }
  if (tid == 0) cnt_s[pair] = n_valid;
}

// ---------------------------------------------------------------------------
// kernel 3: fused greedy NMS (replaces matrix k_iou + k_scan; no global mat).
// 1 block (8 waves) per pair. 16 chunks of 64 boxes processed in order:
//   Phase A (all waves): suppress chunk lanes vs KEPT-so-far list only.
//   Phase B (all waves): intra-chunk 64x64 row masks via ballots.
//   Resolve (wave 0):    serial 64-step greedy walk, rows in registers+shfl.
// Suppression only from kept boxes == reference `alive = keep[i] & valid[i]`.
// keepm layout identical to round-3 k_scan output.
// ---------------------------------------------------------------------------
__global__ __launch_bounds__(512) void k_nms(const float* __restrict__ boxes_s,
    const float* __restrict__ area_s, const int* __restrict__ cnt_s,
    u64* __restrict__ keepm) {
  int pair = blockIdx.x;
  int tid = threadIdx.x;
  int lane = tid & 63, wv = tid >> 6;   // 8 waves
  __shared__ float4 sbox[KNMS];
  __shared__ float sarea[KNMS];
  __shared__ unsigned short klist[KNMS];
  __shared__ u64 psup[8];
  __shared__ u64 rowm[64];
  __shared__ int s_kn;
  int cnt = cnt_s[pair];
  for (int i = tid; i < KNMS; i += 512) {
    sbox[i] = ((const float4*)boxes_s)[(size_t)pair * KP + i];
    sarea[i] = area_s[(size_t)pair * KP + i];
  }
  __syncthreads();
  int kn = 0;
  for (int t = 0; t < 16; ++t) {
    int j = t * 64 + lane;
    float4 bj; float aj;
    if (j < KNMS) { bj = sbox[j]; aj = sarea[j]; }
    else { bj = make_float4(0.f, 0.f, 0.f, 0.f); aj = 0.f; }
    // Phase A: vs kept boxes from previous chunks (i < t*64 <= j always)
    bool sup = false;
    for (int idx = wv; idx < kn; idx += 8) {
      int i = klist[idx];
      sup |= iou_gt(sbox[i], sarea[i], bj, aj);
      if (__ballot(!sup) == 0ull) break;   // whole wave suppressed
    }
    u64 bal = __ballot(sup);
    if (lane == 0) psup[wv] = bal;
    int nrow = cnt - t * 64;
    nrow = nrow < 0 ? 0 : (nrow > 64 ? 64 : nrow);
    __syncthreads();                       // psup ready; rowm free
    // Phase B: intra-chunk rows (row i = ballot over lanes j of suppress(i,j))
    for (int il = wv; il < nrow; il += 8) {
      int i = t * 64 + il;
      bool pred = (il < lane) && (j < KNMS) &&
                  iou_gt(sbox[i], sarea[i], bj, aj);
      u64 row = __ballot(pred);
      if (lane == 0) rowm[il] = row;
    }
    __syncthreads();                       // rowm ready
    if (wv == 0) {
      u64 prior = psup[0] | psup[1] | psup[2] | psup[3] |
                  psup[4] | psup[5] | psup[6] | psup[7];
      u64 valid = (nrow >= 64) ? ~0ull
                : ((nrow > 0) ? ((1ull << nrow) - 1ull) : 0ull);
      u64 rowv = (lane < nrow) ? rowm[lane] : 0ull;
      u64 rem = valid & ~prior;
      u64 keep = 0ull;
      while (rem) {                        // uniform across wave 0
        int i = __ffsll((long long)rem) - 1;
        keep |= 1ull << i;
        u64 row = __shfl(rowv, i);
        rem &= ~(1ull << i);
        rem &= ~row;
      }
      if ((keep >> lane) & 1ull) {
        int pos = (int)__popcll(keep & ((1ull << lane) - 1ull));
        klist[kn + pos] = (unsigned short)(t * 64 + lane);
      }
      if (lane == 0) {
        keepm[pair * 16 + t] = keep;
        s_kn = kn + (int)__popcll(keep);
      }
    }
    __syncthreads();                       // klist/s_kn visible
    kn = s_kn;
  }
}

// ---------------------------------------------------------------------------
// kernel 5a: per pair: emit top-min(mb,kept) kept keys (scores_s is sorted,
// so the first set bits ARE the best). 1 wave per pair.
// key = (score_bits << 32) | ~(c*KNMS + k)
// ---------------------------------------------------------------------------
__global__ __launch_bounds__(64) void k_fa(const u64* __restrict__ keepm,
    const float* __restrict__ scores_s, u64* __restrict__ fa, int C, int mb) {
  int pair = blockIdx.x;
  int lane = threadIdx.x;
  int c = pair % C;
  u64 kw = (lane < 16) ? keepm[pair * 16 + lane] : 0ull;
  int pc = __popcll(kw);
  int scan = pc;
  for (int d = 1; d < 16; d <<= 1) {
    int o = __shfl_up(scan, d);
    if (lane >= d) scan += o;
  }
  int base = scan - pc;
  int total = __shfl(scan, 15);
  if (lane < 16) {
    u64 m = kw; int r = base;
    while (m && r < mb) {
      int bit = __ffsll((long long)m) - 1; m &= m - 1;
      int k = lane * 64 + bit;
      float s = scores_s[(size_t)pair * KP + k];
      fa[(size_t)pair * mb + r] =
          ((u64)__float_as_uint(s) << 32) | (unsigned)(~(unsigned)(c * KNMS + k));
      r++;
    }
  }
  int start = total < mb ? total : mb;
  for (int r = start + lane; r < mb; r += 64) fa[(size_t)pair * mb + r] = 0ull;
}

// ---------------------------------------------------------------------------
// kernel 5b: per batch: sort C*mb candidate keys desc, write outputs.
// ---------------------------------------------------------------------------
__global__ __launch_bounds__(1024) void k_fb(const u64* __restrict__ fa,
    const float* __restrict__ boxes_s, float* __restrict__ out,
    int B, int C, int mb) {
  int b = blockIdx.x, tid = threadIdx.x;
  __shared__ u64 cand[FBN];
  int nk = C * mb; if (nk > FBN) nk = FBN;
  const u64* src = fa + (size_t)b * C * mb;
  for (int i = tid; i < FBN; i += 1024) cand[i] = (i < nk) ? src[i] : 0ull;
  __syncthreads();
  bitonic_desc<FBN, 1024>(cand, tid);
  for (int k = tid; k < mb; k += 1024) {
    u64 key = cand[k];
    float4 bx = make_float4(0.f, 0.f, 0.f, 0.f);
    float sc = 0.f, cf = -1.f;
    if (key != 0ull) {
      sc = __uint_as_float((unsigned)(key >> 32));
      unsigned flat = ~(unsigned)key;
      int c = flat / KNMS;
      int kk = flat - c * KNMS;
      bx = ((const float4*)boxes_s)[(size_t)(b * C + c) * KP + kk];
      cf = (float)c;
    }
    size_t ro = (size_t)(b * mb + k) * 4;
    out[ro + 0] = bx.x; out[ro + 1] = bx.y; out[ro + 2] = bx.z; out[ro + 3] = bx.w;
    out[(size_t)B * mb * 4 + b * mb + k] = sc;
    out[(size_t)B * mb * 5 + b * mb + k] = cf;
  }
}

// ---------------------------------------------------------------------------
extern "C" void kernel_launch(void* const* d_in, const int* in_sizes, int n_in,
                              void* d_out, int out_size, void* d_ws, size_t ws_size,
                              hipStream_t stream) {
  const float* classification = (const float*)d_in[3];
  const float* tanch = (const float*)d_in[4];
  const float* thr_p = (const float*)d_in[5];

  int B = in_sizes[0] / (3 * 64 * 64);
  if (B <= 0) B = 4;
  long long BA = (long long)in_sizes[4] / 4;
  int A = (int)(BA / B);
  int C = (int)((long long)in_sizes[3] / BA);
  int NP = B * C;
  int mb = out_size / (B * 6);

  auto rsz = [](size_t x) { return (x + 255) & ~(size_t)255; };
  size_t clsT_bytes = rsz((size_t)NP * A * 4);
  size_t rest = rsz((size_t)NP * KP * 4)       // scores
              + rsz((size_t)NP * KP * 16)      // boxes
              + rsz((size_t)NP * KP * 4)       // areas
              + rsz((size_t)NP * 4)            // counts
              + rsz((size_t)NP * 16 * 8)       // keep masks
              + rsz((size_t)NP * NBIN * 4)     // ghist
              + rsz((size_t)NP * 4)            // gcnt
              + rsz((size_t)NP * 4)            // cut
              + rsz((size_t)NP * CAP * 8)      // gcand
              + rsz((size_t)NP * mb * 8);      // fa
  int use_t = (C <= 127 && ws_size >= rest + clsT_bytes) ? 1 : 0;

  size_t off = 0;
  auto take = [&](size_t bytes) {
    void* p = (char*)d_ws + off;
    off += rsz(bytes);
    return p;
  };
  float* clsT = nullptr;
  if (use_t) clsT = (float*)take((size_t)NP * A * 4);
  float* scores_s = (float*)take((size_t)NP * KP * 4);
  float* boxes_s  = (float*)take((size_t)NP * KP * 16);
  float* area_s   = (float*)take((size_t)NP * KP * 4);
  int*   cnt_s    = (int*)take((size_t)NP * 4);
  u64*   keepm    = (u64*)take((size_t)NP * 16 * 8);
  unsigned int* ghist = (unsigned int*)take((size_t)NP * NBIN * 4);
  int*   gcnt     = (int*)take((size_t)NP * 4);
  unsigned int* cut = (unsigned int*)take((size_t)NP * 4);
  u64*   gcand    = (u64*)take((size_t)NP * CAP * 8);
  u64*   fa       = (u64*)take((size_t)NP * mb * 8);

  hipMemsetAsync(ghist, 0, (size_t)NP * NBIN * 4, stream);
  hipMemsetAsync(gcnt, 0, (size_t)NP * 4, stream);

  if (use_t)
    k_transpose<<<dim3((A + 63) / 64, B), 256, 0, stream>>>(classification, clsT, A, C);
  const float* cl = use_t ? clsT : classification;
  k_hist<<<dim3(NP, SLC), 256, 0, stream>>>(cl, use_t, thr_p, ghist, A, C);
  k_cutoff<<<NP, 512, 0, stream>>>(ghist, cut);
  k_compact<<<dim3(NP, SLC), 256, 0, stream>>>(cl, use_t, thr_p, cut, gcnt, gcand, A, C);
  k_sortpairs<<<NP, 1024, 0, stream>>>(gcand, gcnt, tanch, scores_s, boxes_s, area_s, cnt_s, A, C);
  k_nms<<<NP, 512, 0, stream>>>(boxes_s, area_s, cnt_s, keepm);
  k_fa<<<NP, 64, 0, stream>>>(keepm, scores_s, fa, C, mb);
  k_fb<<<B, 1024, 0, stream>>>(fa, boxes_s, (float*)d_out, B, C, mb);
}

// Round 5
// 679.880 us; speedup vs baseline: 1.0605x; 1.0605x over previous
//
#include <hip/hip_runtime.h>
#include <hip/hip_bf16.h>

typedef unsigned long long u64;

#define KNMS 1000      // MAX_BOX_PRE_NMS (hardcoded in reference)
#define KP   1024      // padded stride for per-pair arrays
#define CAP  4096      // candidate capacity per pair
#define NBIN 8192      // radix-select histogram bins (score bits >> 18)
#define SLC  8         // A-dimension splits for hist/compact
#define FBN  8192      // final per-batch sort size (>= C*mb)
#define IOU_THR 0.5f

#define NEGINF __uint_as_float(0xFF800000u)

// ---------------------------------------------------------------------------
// helpers
// ---------------------------------------------------------------------------

// Find the histogram bin containing rank `rank` counting from the TOP.
__device__ __forceinline__ void find_cutoff(unsigned int* hist, int nbins,
    unsigned int* csum, int nthreads, int tid, unsigned int rank,
    unsigned int* s_bin, unsigned int* s_gt, unsigned int* s_total, int* s_all) {
  int chunk = nbins / nthreads;
  unsigned int cs = 0;
  int base = tid * chunk;
  for (int q = 0; q < chunk; q++) cs += hist[base + q];
  csum[tid] = cs;
  __syncthreads();
  if (tid == 0) {
    unsigned int total = 0;
    for (int ch = 0; ch < nthreads; ch++) total += csum[ch];
    *s_total = total;
    if (total <= rank) { *s_bin = 0u; *s_gt = 0u; *s_all = 1; }
    else {
      unsigned int acc = 0; int ch = nthreads - 1;
      while (acc + csum[ch] < rank) { acc += csum[ch]; ch--; }
      int bin = ch * chunk + chunk - 1;
      while (acc + hist[bin] < rank) { acc += hist[bin]; bin--; }
      *s_bin = (unsigned)bin; *s_gt = acc; *s_all = 0;
    }
  }
  __syncthreads();
}

// In-LDS bitonic sort, descending, 64-bit keys.
template<int N, int NT>
__device__ __forceinline__ void bitonic_desc(u64* a, int tid) {
  for (int k = 2; k <= N; k <<= 1) {
    for (int j = k >> 1; j > 0; j >>= 1) {
      for (int t = tid; t < N; t += NT) {
        int ixj = t ^ j;
        if (ixj > t) {
          u64 x = a[t], y = a[ixj];
          if (((t & k) == 0) ? (x < y) : (x > y)) { a[t] = y; a[ixj] = x; }
        }
      }
      __syncthreads();
    }
  }
}

// Bit-exact greedy-NMS predicate vs reference:
// fl(inter/uni) > 0.5  <=>  2*inter > uni*(1+2^-24), exact in f64
// (24-bit x 25-bit mantissas fit 53 bits; midpoint ties round to even 0.5;
//  inter=uni=0 -> NaN -> false on both sides; uni<0 impossible).
__device__ __forceinline__ bool iou_gt(float4 bi, float ai, float4 bj, float aj) {
  float ltx = fmaxf(bi.x, bj.x), lty = fmaxf(bi.y, bj.y);
  float rbx = fminf(bi.z, bj.z), rby = fminf(bi.w, bj.w);
  float ww = fmaxf(rbx - ltx, 0.f), hh = fmaxf(rby - lty, 0.f);
  float inter = ww * hh;
  float uni = (ai + aj) - inter;
  return ((double)inter * 2.0 > (double)uni * (1.0 + 0x1p-24));
}

// ---------------------------------------------------------------------------
// kernel 1: transpose classification [B,A,C] -> [B,C,A]  (C <= 127)
// ---------------------------------------------------------------------------
__global__ __launch_bounds__(256) void k_transpose(const float* __restrict__ src0,
    float* __restrict__ dst0, int A, int C) {
  __shared__ float tile[64 * 129];
  int b = blockIdx.y;
  int a0 = blockIdx.x * 64;
  const float* src = src0 + (size_t)b * A * C;
  float* dst = dst0 + (size_t)b * A * C;
  int st = C + 1;
  for (int idx = threadIdx.x; idx < 64 * C; idx += 256) {
    int al = idx / C, c = idx - al * C;
    int a = a0 + al;
    tile[al * st + c] = (a < A) ? src[(size_t)a * C + c] : 0.f;
  }
  __syncthreads();
  for (int idx = threadIdx.x; idx < 64 * C; idx += 256) {
    int c = idx >> 6, al = idx & 63;
    int a = a0 + al;
    if (a < A) dst[(size_t)c * A + a] = tile[al * st + c];
  }
}

// ---------------------------------------------------------------------------
// kernel 2a: per (pair, slice): LDS histogram of score bits>>18, merged to
// global hist via non-returning atomics (only ~32 nonzero bins/block).
// ---------------------------------------------------------------------------
__global__ __launch_bounds__(256) void k_hist(const float* __restrict__ cls,
    int transposed, const float* __restrict__ thr_p,
    unsigned int* __restrict__ ghist, int A, int C) {
  int pair = blockIdx.x, s = blockIdx.y, tid = threadIdx.x;
  int b = pair / C, c = pair - b * C;
  const float* col; int str;
  if (transposed) { col = cls + (size_t)pair * A; str = 1; }
  else            { col = cls + (size_t)b * A * C + c; str = C; }
  float thr = *thr_p;
  __shared__ unsigned int lh[NBIN];
  for (int i = tid; i < NBIN; i += 256) lh[i] = 0u;
  __syncthreads();
  bool vec = (str == 1) && ((A & 3) == 0);
  if (vec) {
    const float4* col4 = (const float4*)col;
    int A4 = A >> 2;
    int n4 = (A4 + SLC - 1) / SLC, i0 = s * n4, i1 = min(A4, i0 + n4);
    for (int i = i0 + tid; i < i1; i += 256) {
      float4 v = col4[i];
      float vv[4] = {v.x, v.y, v.z, v.w};
#pragma unroll
      for (int q = 0; q < 4; q++)
        if (vv[q] > thr) atomicAdd(&lh[__float_as_uint(vv[q]) >> 18], 1u);
    }
  } else {
    int nE = (A + SLC - 1) / SLC, a0 = s * nE, a1 = min(A, a0 + nE);
    for (int a = a0 + tid; a < a1; a += 256) {
      float sv = col[(size_t)a * str];
      if (sv > thr) atomicAdd(&lh[__float_as_uint(sv) >> 18], 1u);
    }
  }
  __syncthreads();
  unsigned int* gh = ghist + (size_t)pair * NBIN;
  for (int i = tid; i < NBIN; i += 256) {
    unsigned v = lh[i];
    if (v) atomicAdd(&gh[i], v);
  }
}

// ---------------------------------------------------------------------------
// kernel 2b: per pair: find cutoff bin for rank KNMS. cut=0 means take-all.
// Margin: bin width 2^-18 -> boundary-bin count ~1.6K for this workload;
// takers <= ~2.6K << CAP=4096.
// ---------------------------------------------------------------------------
__global__ __launch_bounds__(512) void k_cutoff(const unsigned int* __restrict__ ghist,
    unsigned int* __restrict__ cut) {
  int pair = blockIdx.x, tid = threadIdx.x;
  __shared__ unsigned int lh[NBIN];
  __shared__ unsigned int csum[512];
  __shared__ unsigned int s_b1, s_gt, s_tot;
  __shared__ int s_all;
  const unsigned int* gh = ghist + (size_t)pair * NBIN;
  for (int i = tid; i < NBIN; i += 512) lh[i] = gh[i];
  __syncthreads();
  find_cutoff(lh, NBIN, csum, 512, tid, KNMS, &s_b1, &s_gt, &s_tot, &s_all);
  if (tid == 0) cut[pair] = s_all ? 0u : s_b1;
}

// ---------------------------------------------------------------------------
// kernel 2c: per (pair, slice): compact keys with bin >= cut. LDS staging,
// one returning global atomic per BLOCK, bulk coalesced dump.
// key = (score_bits << 32) | ~anchor_index (stable: low index wins ties)
// ---------------------------------------------------------------------------
__global__ __launch_bounds__(256) void k_compact(const float* __restrict__ cls,
    int transposed, const float* __restrict__ thr_p,
    const unsigned int* __restrict__ cut, int* __restrict__ gcnt,
    u64* __restrict__ gcand, int A, int C) {
  int pair = blockIdx.x, s = blockIdx.y, tid = threadIdx.x;
  int b = pair / C, c = pair - b * C;
  const float* col; int str;
  if (transposed) { col = cls + (size_t)pair * A; str = 1; }
  else            { col = cls + (size_t)b * A * C + c; str = C; }
  float thr = *thr_p;
  unsigned b1 = cut[pair];

  __shared__ u64 sbuf[CAP];
  __shared__ int s_n, s_base;
  if (tid == 0) s_n = 0;
  __syncthreads();

  int lane = tid & 63;
  auto stage = [&](u64 key, bool take) {
    u64 m = __ballot(take);
    if (!m) return;
    int ldr = __ffsll((long long)m) - 1;
    int base = 0;
    if (lane == ldr) base = atomicAdd(&s_n, (int)__popcll(m));
    base = __shfl(base, ldr);
    if (take) {
      int pos = base + (int)__popcll(m & ((1ull << lane) - 1ull));
      if (pos < CAP) sbuf[pos] = key;
    }
  };

  bool vec = (str == 1) && ((A & 3) == 0);
  if (vec) {
    const float4* col4 = (const float4*)col;
    int A4 = A >> 2;
    int n4 = (A4 + SLC - 1) / SLC, i0 = s * n4, i1 = min(A4, i0 + n4);
    for (int i = i0 + tid; i < i1; i += 256) {
      float4 v = col4[i];
      float vv[4] = {v.x, v.y, v.z, v.w};
#pragma unroll
      for (int q = 0; q < 4; q++) {
        float sv = vv[q];
        unsigned bits = __float_as_uint(sv);
        bool take = (sv > thr) && ((bits >> 18) >= b1);
        u64 key = ((u64)bits << 32) | (unsigned)(~(unsigned)(i * 4 + q));
        stage(key, take);
      }
    }
  } else {
    int nE = (A + SLC - 1) / SLC, a0 = s * nE, a1 = min(A, a0 + nE);
    for (int a = a0 + tid; a < a1; a += 256) {
      float sv = col[(size_t)a * str];
      unsigned bits = __float_as_uint(sv);
      bool take = (sv > thr) && ((bits >> 18) >= b1);
      u64 key = ((u64)bits << 32) | (unsigned)(~(unsigned)a);
      stage(key, take);
    }
  }
  __syncthreads();
  int n = s_n < CAP ? s_n : CAP;
  if (tid == 0) s_base = atomicAdd(&gcnt[pair], s_n);  // true total (unclamped)
  __syncthreads();
  int base = s_base;
  u64* dst = gcand + (size_t)pair * CAP;
  for (int t = tid; t < n; t += 256) {
    int pos = base + t;
    if (pos < CAP) dst[pos] = sbuf[t];
  }
}

// ---------------------------------------------------------------------------
// kernel 2d: per pair: sort candidates desc, gather boxes, write sorted arrays
// ---------------------------------------------------------------------------
__global__ __launch_bounds__(1024) void k_sortpairs(const u64* __restrict__ gcand,
    const int* __restrict__ gcnt, const float* __restrict__ tanch,
    float* __restrict__ scores_s, float* __restrict__ boxes_s,
    float* __restrict__ area_s, int* __restrict__ cnt_s, int A, int C) {
  int pair = blockIdx.x, tid = threadIdx.x;
  int b = pair / C;
  __shared__ u64 cand[CAP];
  int nc = gcnt[pair];
  int n = nc < CAP ? nc : CAP;
  for (int t = tid; t < CAP; t += 1024)
    cand[t] = (t < n) ? gcand[(size_t)pair * CAP + t] : 0ull;
  __syncthreads();
  bitonic_desc<CAP, 1024>(cand, tid);
  int n_valid = nc < KNMS ? nc : KNMS;
  for (int k = tid; k < KNMS; k += 1024) {
    u64 key = cand[k];
    float sc; float4 bx; float ar;
    if (k < n_valid && key != 0ull) {
      sc = __uint_as_float((unsigned)(key >> 32));
      unsigned a = ~(unsigned)key;
      bx = ((const float4*)tanch)[(size_t)b * A + a];
      ar = (bx.z - bx.x) * (bx.w - bx.y);
    } else {
      sc = NEGINF; bx = make_float4(0.f, 0.f, 0.f, 0.f); ar = 0.f;
    }
    scores_s[(size_t)pair * KP + k] = sc;
    ((float4*)boxes_s)[(size_t)pair * KP + k] = bx;
    area_s[(size_t)pair * KP + k] = ar;
  }
  if (tid == 0) cnt_s[pair] = n_valid;
}

// ---------------------------------------------------------------------------
// kernel 3: suppression matrix, TRANSPOSED layout mat[pair][w][i]:
// bit (j-w*64) of mat[pair][w*KP+i] = suppress(i -> j), j in [w*64, w*64+64).
// Round-3 pathology fixed: words accumulate in LDS rowm[] and are dumped as
// one contiguous 8KB strip per block (coalesced), instead of lane0-only 8B
// stores at 128B stride (175MB -> 42MB HBM writes).
// ---------------------------------------------------------------------------
__global__ __launch_bounds__(256) void k_iou(const float* __restrict__ boxes_s,
    const float* __restrict__ area_s, const int* __restrict__ cnt_s,
    u64* __restrict__ mat) {
  int pair = blockIdx.x, w = blockIdx.y;
  int cnt = cnt_s[pair];
  int lim = (w + 1) * 64; if (lim > KNMS) lim = KNMS;  // rows needed: i <= w*64+62; plus own chunk
  __shared__ float4 sbox[KNMS];
  __shared__ float sarea[KNMS];
  __shared__ u64 rowm[KP];
  for (int i = threadIdx.x; i < lim; i += 256) {
    sbox[i] = ((const float4*)boxes_s)[(size_t)pair * KP + i];
    sarea[i] = area_s[(size_t)pair * KP + i];
  }
  for (int i = threadIdx.x; i < KP; i += 256) rowm[i] = 0ull;
  __syncthreads();
  int lane = threadIdx.x & 63, wv = threadIdx.x >> 6;
  int j = w * 64 + lane;
  bool jok = j < KNMS;
  float4 bj = (jok) ? sbox[j] : make_float4(0.f, 0.f, 0.f, 0.f);
  float aj = (jok) ? sarea[j] : 0.f;
  int rowLim = cnt < (w * 64 + 63) ? cnt : (w * 64 + 63);
  for (int i = wv; i < rowLim; i += 4) {
    float4 bi = sbox[i]; float ai = sarea[i];
    bool sup = jok && (j > i) && iou_gt(bi, ai, bj, aj);
    u64 word = __ballot(sup);
    if (lane == 0) rowm[i] = word;
  }
  __syncthreads();
  u64* dst = mat + ((size_t)pair * 16 + w) * KP;
  for (int t = threadIdx.x; t < cnt; t += 256) dst[t] = rowm[t];
}

// ---------------------------------------------------------------------------
// kernel 4: serial greedy scan. 1 wave per pair; lanes 0..15 own keep-words.
// Reads transposed mat[pair][lane][i]; the 16-ahead register prefetch makes
// each lane touch 2 consecutive 64B sectors per group (L1-resident).
// ---------------------------------------------------------------------------
__global__ __launch_bounds__(64) void k_scan(const u64* __restrict__ mat,
    const int* __restrict__ cnt_s, u64* __restrict__ keep_out) {
  int pair = blockIdx.x;
  int lane = threadIdx.x;
  int cnt = cnt_s[pair];
  const u64* m = mat + (size_t)pair * KP * 16 + (size_t)lane * KP;
  u64 keepw = 0ull;
  if (lane < 16) {
    int nb = cnt - lane * 64;
    nb = nb < 0 ? 0 : (nb > 64 ? 64 : nb);
    keepw = (nb >= 64) ? ~0ull : ((nb > 0) ? ((1ull << nb) - 1ull) : 0ull);
  }
  bool ld = lane < 16;
  u64 cur[16], nxt[16];
#pragma unroll
  for (int r = 0; r < 16; r++) cur[r] = (ld && r < cnt) ? m[r] : 0ull;
  for (int g = 0; g < cnt; g += 16) {
#pragma unroll
    for (int r = 0; r < 16; r++) {
      int i = g + 16 + r;
      nxt[r] = (ld && i < cnt) ? m[i] : 0ull;
    }
#pragma unroll
    for (int r = 0; r < 16; r++) {
      int i = g + r;
      if (i < cnt) {
        u64 kw = __shfl(keepw, i >> 6);
        if ((kw >> (i & 63)) & 1ull) keepw &= ~cur[r];
      }
      cur[r] = nxt[r];
    }
  }
  if (lane < 16) keep_out[pair * 16 + lane] = keepw;
}

// ---------------------------------------------------------------------------
// kernel 5a: per pair: emit top-min(mb,kept) kept keys (scores_s is sorted,
// so the first set bits ARE the best). 1 wave per pair.
// key = (score_bits << 32) | ~(c*KNMS + k)
// ---------------------------------------------------------------------------
__global__ __launch_bounds__(64) void k_fa(const u64* __restrict__ keepm,
    const float* __restrict__ scores_s, u64* __restrict__ fa, int C, int mb) {
  int pair = blockIdx.x;
  int lane = threadIdx.x;
  int c = pair % C;
  u64 kw = (lane < 16) ? keepm[pair * 16 + lane] : 0ull;
  int pc = __popcll(kw);
  int scan = pc;
  for (int d = 1; d < 16; d <<= 1) {
    int o = __shfl_up(scan, d);
    if (lane >= d) scan += o;
  }
  int base = scan - pc;
  int total = __shfl(scan, 15);
  if (lane < 16) {
    u64 m = kw; int r = base;
    while (m && r < mb) {
      int bit = __ffsll((long long)m) - 1; m &= m - 1;
      int k = lane * 64 + bit;
      float s = scores_s[(size_t)pair * KP + k];
      fa[(size_t)pair * mb + r] =
          ((u64)__float_as_uint(s) << 32) | (unsigned)(~(unsigned)(c * KNMS + k));
      r++;
    }
  }
  int start = total < mb ? total : mb;
  for (int r = start + lane; r < mb; r += 64) fa[(size_t)pair * mb + r] = 0ull;
}

// ---------------------------------------------------------------------------
// kernel 5b: per batch: sort C*mb candidate keys desc, write outputs.
// ---------------------------------------------------------------------------
__global__ __launch_bounds__(1024) void k_fb(const u64* __restrict__ fa,
    const float* __restrict__ boxes_s, float* __restrict__ out,
    int B, int C, int mb) {
  int b = blockIdx.x, tid = threadIdx.x;
  __shared__ u64 cand[FBN];
  int nk = C * mb; if (nk > FBN) nk = FBN;
  const u64* src = fa + (size_t)b * C * mb;
  for (int i = tid; i < FBN; i += 1024) cand[i] = (i < nk) ? src[i] : 0ull;
  __syncthreads();
  bitonic_desc<FBN, 1024>(cand, tid);
  for (int k = tid; k < mb; k += 1024) {
    u64 key = cand[k];
    float4 bx = make_float4(0.f, 0.f, 0.f, 0.f);
    float sc = 0.f, cf = -1.f;
    if (key != 0ull) {
      sc = __uint_as_float((unsigned)(key >> 32));
      unsigned flat = ~(unsigned)key;
      int c = flat / KNMS;
      int kk = flat - c * KNMS;
      bx = ((const float4*)boxes_s)[(size_t)(b * C + c) * KP + kk];
      cf = (float)c;
    }
    size_t ro = (size_t)(b * mb + k) * 4;
    out[ro + 0] = bx.x; out[ro + 1] = bx.y; out[ro + 2] = bx.z; out[ro + 3] = bx.w;
    out[(size_t)B * mb * 4 + b * mb + k] = sc;
    out[(size_t)B * mb * 5 + b * mb + k] = cf;
  }
}

// ---------------------------------------------------------------------------
extern "C" void kernel_launch(void* const* d_in, const int* in_sizes, int n_in,
                              void* d_out, int out_size, void* d_ws, size_t ws_size,
                              hipStream_t stream) {
  const float* classification = (const float*)d_in[3];
  const float* tanch = (const float*)d_in[4];
  const float* thr_p = (const float*)d_in[5];

  int B = in_sizes[0] / (3 * 64 * 64);
  if (B <= 0) B = 4;
  long long BA = (long long)in_sizes[4] / 4;
  int A = (int)(BA / B);
  int C = (int)((long long)in_sizes[3] / BA);
  int NP = B * C;
  int mb = out_size / (B * 6);

  auto rsz = [](size_t x) { return (x + 255) & ~(size_t)255; };
  size_t clsT_bytes = rsz((size_t)NP * A * 4);
  size_t rest = rsz((size_t)NP * KP * 4)       // scores
              + rsz((size_t)NP * KP * 16)      // boxes
              + rsz((size_t)NP * KP * 4)       // areas
              + rsz((size_t)NP * 4)            // counts
              + rsz((size_t)NP * KP * 16 * 8)  // suppression matrix (+aliases)
              + rsz((size_t)NP * 16 * 8);      // keep masks
  int use_t = (C <= 127 && ws_size >= rest + clsT_bytes) ? 1 : 0;

  size_t off = 0;
  auto take = [&](size_t bytes) {
    void* p = (char*)d_ws + off;
    off += rsz(bytes);
    return p;
  };
  float* clsT = nullptr;
  if (use_t) clsT = (float*)take((size_t)NP * A * 4);
  float* scores_s = (float*)take((size_t)NP * KP * 4);
  float* boxes_s  = (float*)take((size_t)NP * KP * 16);
  float* area_s   = (float*)take((size_t)NP * KP * 4);
  int*   cnt_s    = (int*)take((size_t)NP * 4);
  u64*   mat      = (u64*)take((size_t)NP * KP * 16 * 8);
  u64*   keepm    = (u64*)take((size_t)NP * 16 * 8);

  // Alias selection/final scratch into the mat region (disjoint lifetimes:
  // ghist/gcnt/cut/gcand die before k_iou writes mat; fa is written after
  // k_scan's last read of mat). Total aliased ~21.2 MB <= 41.9 MB.
  char* matc = (char*)mat;
  size_t ao = 0;
  unsigned int* ghist = (unsigned int*)(matc + ao); ao += rsz((size_t)NP * NBIN * 4);
  int* gcnt           = (int*)(matc + ao);          ao += rsz((size_t)NP * 4);
  unsigned int* cut   = (unsigned int*)(matc + ao); ao += rsz((size_t)NP * 4);
  u64* gcand          = (u64*)(matc + ao);          ao += rsz((size_t)NP * CAP * 8);
  u64* fa             = (u64*)(matc + ao);          ao += rsz((size_t)NP * mb * 8);

  hipMemsetAsync(ghist, 0, (size_t)NP * NBIN * 4, stream);
  hipMemsetAsync(gcnt, 0, (size_t)NP * 4, stream);

  if (use_t)
    k_transpose<<<dim3((A + 63) / 64, B), 256, 0, stream>>>(classification, clsT, A, C);
  const float* cl = use_t ? clsT : classification;
  k_hist<<<dim3(NP, SLC), 256, 0, stream>>>(cl, use_t, thr_p, ghist, A, C);
  k_cutoff<<<NP, 512, 0, stream>>>(ghist, cut);
  k_compact<<<dim3(NP, SLC), 256, 0, stream>>>(cl, use_t, thr_p, cut, gcnt, gcand, A, C);
  k_sortpairs<<<NP, 1024, 0, stream>>>(gcand, gcnt, tanch, scores_s, boxes_s, area_s, cnt_s, A, C);
  k_iou<<<dim3(NP, 16), 256, 0, stream>>>(boxes_s, area_s, cnt_s, mat);
  k_scan<<<NP, 64, 0, stream>>>(mat, cnt_s, keepm);
  k_fa<<<NP, 64, 0, stream>>>(keepm, scores_s, fa, C, mb);
  k_fb<<<B, 1024, 0, stream>>>(fa, boxes_s, (float*)d_out, B, C, mb);
}

// Round 6
// 645.812 us; speedup vs baseline: 1.1164x; 1.0528x over previous
//
#include <hip/hip_runtime.h>
#include <hip/hip_bf16.h>

typedef unsigned long long u64;

#define KNMS 1000      // MAX_BOX_PRE_NMS (hardcoded in reference)
#define KP   1024      // padded stride for per-pair arrays
#define CAP  4096      // candidate capacity per pair
#define NBIN 8192      // radix-select histogram bins (score bits >> 18)
#define FBN  8192      // final per-batch sort size (>= C*mb)
#define IOU_THR 0.5f

#define NEGINF __uint_as_float(0xFF800000u)

// ---------------------------------------------------------------------------
// helpers
// ---------------------------------------------------------------------------

// Find the histogram bin containing rank `rank` counting from the TOP.
__device__ __forceinline__ void find_cutoff(unsigned int* hist, int nbins,
    unsigned int* csum, int nthreads, int tid, unsigned int rank,
    unsigned int* s_bin, unsigned int* s_gt, unsigned int* s_total, int* s_all) {
  int chunk = nbins / nthreads;
  unsigned int cs = 0;
  int base = tid * chunk;
  for (int q = 0; q < chunk; q++) cs += hist[base + q];
  csum[tid] = cs;
  __syncthreads();
  if (tid == 0) {
    unsigned int total = 0;
    for (int ch = 0; ch < nthreads; ch++) total += csum[ch];
    *s_total = total;
    if (total <= rank) { *s_bin = 0u; *s_gt = 0u; *s_all = 1; }
    else {
      unsigned int acc = 0; int ch = nthreads - 1;
      while (acc + csum[ch] < rank) { acc += csum[ch]; ch--; }
      int bin = ch * chunk + chunk - 1;
      while (acc + hist[bin] < rank) { acc += hist[bin]; bin--; }
      *s_bin = (unsigned)bin; *s_gt = acc; *s_all = 0;
    }
  }
  __syncthreads();
}

// In-LDS bitonic sort, descending, 64-bit keys.
template<int N, int NT>
__device__ __forceinline__ void bitonic_desc(u64* a, int tid) {
  for (int k = 2; k <= N; k <<= 1) {
    for (int j = k >> 1; j > 0; j >>= 1) {
      for (int t = tid; t < N; t += NT) {
        int ixj = t ^ j;
        if (ixj > t) {
          u64 x = a[t], y = a[ixj];
          if (((t & k) == 0) ? (x < y) : (x > y)) { a[t] = y; a[ixj] = x; }
        }
      }
      __syncthreads();
    }
  }
}

// Bit-exact greedy-NMS predicate vs reference, PURE f32:
//   fl(inter/uni) > 0.5  <=>  2*inter > uni*(1+2^-24)   (reals; uni>=0)
// The sign of 2I - U(1+2^-24) is only in doubt when U/2 <= 2I <= 2U, which is
// exactly the Sterbenz range where q = (I+I) - U is EXACT in f32; there
// t = U*2^-24 is exact too (power-of-2 scale), so q > t decides exactly.
// Outside Sterbenz the rounded q has a decisive sign (|2I-U| >= U/2 up to
// 1 ulp, far beyond t). Exact ties at the midpoint are unrepresentable in
// f32 (would need a 25-bit mantissa). I=U=0 (padding): q=0,t=0 -> false,
// matching the reference's 0/0=NaN > 0.5 = false.
__device__ __forceinline__ bool iou_gt(float4 bi, float ai, float4 bj, float aj) {
  float ltx = fmaxf(bi.x, bj.x), lty = fmaxf(bi.y, bj.y);
  float rbx = fminf(bi.z, bj.z), rby = fminf(bi.w, bj.w);
  float ww = fmaxf(rbx - ltx, 0.f), hh = fmaxf(rby - lty, 0.f);
  float inter = ww * hh;
  float uni = (ai + aj) - inter;
  float q = (inter + inter) - uni;
  float t = uni * 0x1p-24f;
  return q > t;
}

// ---------------------------------------------------------------------------
// kernel 1: transpose classification [B,A,C] -> [B,C,A]  (C <= 127)
// ---------------------------------------------------------------------------
__global__ __launch_bounds__(256) void k_transpose(const float* __restrict__ src0,
    float* __restrict__ dst0, int A, int C) {
  __shared__ float tile[64 * 129];
  int b = blockIdx.y;
  int a0 = blockIdx.x * 64;
  const float* src = src0 + (size_t)b * A * C;
  float* dst = dst0 + (size_t)b * A * C;
  int st = C + 1;
  for (int idx = threadIdx.x; idx < 64 * C; idx += 256) {
    int al = idx / C, c = idx - al * C;
    int a = a0 + al;
    tile[al * st + c] = (a < A) ? src[(size_t)a * C + c] : 0.f;
  }
  __syncthreads();
  for (int idx = threadIdx.x; idx < 64 * C; idx += 256) {
    int c = idx >> 6, al = idx & 63;
    int a = a0 + al;
    if (a < A) dst[(size_t)c * A + a] = tile[al * st + c];
  }
}

// ---------------------------------------------------------------------------
// kernel 2 (FUSED): per pair, one block of 1024 threads does
//   pass1: block-local LDS histogram of score bits>>18 (no global hist)
//   cutoff: in-block radix-select for rank KNMS
//   pass2: re-read (L3-hot) + compact keys to LDS via wave ballots + ONE
//          LDS counter atomic per ballot (block-local, cheap)
//   sort:  in-LDS bitonic of CAP keys, gather boxes, write sorted arrays
// Replaces k_hist/k_cutoff/k_compact/k_sortpairs + ghist/gcand traffic.
// key = (score_bits << 32) | ~anchor_index (stable: low index wins ties)
// ---------------------------------------------------------------------------
__global__ __launch_bounds__(1024) void k_select(const float* __restrict__ cls,
    int transposed, const float* __restrict__ thr_p,
    const float* __restrict__ tanch,
    float* __restrict__ scores_s, float* __restrict__ boxes_s,
    float* __restrict__ area_s, int* __restrict__ cnt_s, int A, int C) {
  int pair = blockIdx.x, tid = threadIdx.x;
  int b = pair / C, c = pair - b * C;
  const float* col; int str;
  if (transposed) { col = cls + (size_t)pair * A; str = 1; }
  else            { col = cls + (size_t)b * A * C + c; str = C; }
  float thr = *thr_p;

  __shared__ union { unsigned int hist[NBIN]; u64 cand[CAP]; } sh;
  __shared__ unsigned int csum[1024];
  __shared__ unsigned int s_b1, s_gt, s_tot;
  __shared__ int s_all, s_n;

  for (int i = tid; i < NBIN; i += 1024) sh.hist[i] = 0u;
  __syncthreads();

  bool vec = (str == 1) && ((A & 3) == 0);
  if (vec) {
    const float4* col4 = (const float4*)col;
    int A4 = A >> 2;
    for (int i = tid; i < A4; i += 1024) {
      float4 v = col4[i];
      float vv[4] = {v.x, v.y, v.z, v.w};
#pragma unroll
      for (int q = 0; q < 4; q++)
        if (vv[q] > thr) atomicAdd(&sh.hist[__float_as_uint(vv[q]) >> 18], 1u);
    }
  } else {
    for (int a = tid; a < A; a += 1024) {
      float sv = col[(size_t)a * str];
      if (sv > thr) atomicAdd(&sh.hist[__float_as_uint(sv) >> 18], 1u);
    }
  }
  __syncthreads();
  find_cutoff(sh.hist, NBIN, csum, 1024, tid, KNMS, &s_b1, &s_gt, &s_tot, &s_all);
  unsigned b1 = s_all ? 0u : s_b1;   // take-all: every >thr element passes
  unsigned tot = s_tot;
  // hist is dead past this point (find_cutoff ended with a barrier) -> reuse
  for (int t = tid; t < CAP; t += 1024) sh.cand[t] = 0ull;
  if (tid == 0) s_n = 0;
  __syncthreads();

  int lane = tid & 63;
  auto stage = [&](u64 key, bool take) {
    u64 m = __ballot(take);
    if (!m) return;
    int ldr = __ffsll((long long)m) - 1;
    int base = 0;
    if (lane == ldr) base = atomicAdd(&s_n, (int)__popcll(m));  // LDS atomic
    base = __shfl(base, ldr);
    if (take) {
      int pos = base + (int)__popcll(m & ((1ull << lane) - 1ull));
      if (pos < CAP) sh.cand[pos] = key;
    }
  };

  if (vec) {
    const float4* col4 = (const float4*)col;
    int A4 = A >> 2;
    for (int i = tid; i < A4; i += 1024) {
      float4 v = col4[i];
      float vv[4] = {v.x, v.y, v.z, v.w};
#pragma unroll
      for (int q = 0; q < 4; q++) {
        float sv = vv[q];
        unsigned bits = __float_as_uint(sv);
        bool take = (sv > thr) && ((bits >> 18) >= b1);
        u64 key = ((u64)bits << 32) | (unsigned)(~(unsigned)(i * 4 + q));
        stage(key, take);
      }
    }
  } else {
    for (int a = tid; a < A; a += 1024) {
      float sv = col[(size_t)a * str];
      unsigned bits = __float_as_uint(sv);
      bool take = (sv > thr) && ((bits >> 18) >= b1);
      u64 key = ((u64)bits << 32) | (unsigned)(~(unsigned)a);
      stage(key, take);
    }
  }
  __syncthreads();

  bitonic_desc<CAP, 1024>(sh.cand, tid);

  int n_valid = (int)tot < KNMS ? (int)tot : KNMS;
  for (int k = tid; k < KNMS; k += 1024) {
    u64 key = sh.cand[k];
    float sc; float4 bx; float ar;
    if (k < n_valid && key != 0ull) {
      sc = __uint_as_float((unsigned)(key >> 32));
      unsigned a = ~(unsigned)key;
      bx = ((const float4*)tanch)[(size_t)b * A + a];
      ar = (bx.z - bx.x) * (bx.w - bx.y);
    } else {
      sc = NEGINF; bx = make_float4(0.f, 0.f, 0.f, 0.f); ar = 0.f;
    }
    scores_s[(size_t)pair * KP + k] = sc;
    ((float4*)boxes_s)[(size_t)pair * KP + k] = bx;
    area_s[(size_t)pair * KP + k] = ar;
  }
  if (tid == 0) cnt_s[pair] = n_valid;
}

// ---------------------------------------------------------------------------
// kernel 3: suppression matrix, TRANSPOSED layout mat[pair][w][i]:
// bit (j-w*64) of mat[pair][w*KP+i] = suppress(i -> j), j in [w*64, w*64+64).
// LDS-accumulated, coalesced 8KB-strip dump (round-5 structure).
// ---------------------------------------------------------------------------
__global__ __launch_bounds__(256) void k_iou(const float* __restrict__ boxes_s,
    const float* __restrict__ area_s, const int* __restrict__ cnt_s,
    u64* __restrict__ mat) {
  int pair = blockIdx.x, w = blockIdx.y;
  int cnt = cnt_s[pair];
  int lim = (w + 1) * 64; if (lim > KNMS) lim = KNMS;
  __shared__ float4 sbox[KNMS];
  __shared__ float sarea[KNMS];
  __shared__ u64 rowm[KP];
  for (int i = threadIdx.x; i < lim; i += 256) {
    sbox[i] = ((const float4*)boxes_s)[(size_t)pair * KP + i];
    sarea[i] = area_s[(size_t)pair * KP + i];
  }
  for (int i = threadIdx.x; i < KP; i += 256) rowm[i] = 0ull;
  __syncthreads();
  int lane = threadIdx.x & 63, wv = threadIdx.x >> 6;
  int j = w * 64 + lane;
  bool jok = j < KNMS;
  float4 bj = (jok) ? sbox[j] : make_float4(0.f, 0.f, 0.f, 0.f);
  float aj = (jok) ? sarea[j] : 0.f;
  int rowLim = cnt < (w * 64 + 63) ? cnt : (w * 64 + 63);
  for (int i = wv; i < rowLim; i += 4) {
    float4 bi = sbox[i]; float ai = sarea[i];
    bool sup = jok && (j > i) && iou_gt(bi, ai, bj, aj);
    u64 word = __ballot(sup);
    if (lane == 0) rowm[i] = word;
  }
  __syncthreads();
  u64* dst = mat + ((size_t)pair * 16 + w) * KP;
  for (int t = threadIdx.x; t < cnt; t += 256) dst[t] = rowm[t];
}

// ---------------------------------------------------------------------------
// kernel 4: serial greedy scan. 1 wave per pair; lanes 0..15 own keep-words.
// Reads transposed mat[pair][lane][i]; 16-ahead register prefetch.
// ---------------------------------------------------------------------------
__global__ __launch_bounds__(64) void k_scan(const u64* __restrict__ mat,
    const int* __restrict__ cnt_s, u64* __restrict__ keep_out) {
  int pair = blockIdx.x;
  int lane = threadIdx.x;
  int cnt = cnt_s[pair];
  const u64* m = mat + (size_t)pair * KP * 16 + (size_t)lane * KP;
  u64 keepw = 0ull;
  if (lane < 16) {
    int nb = cnt - lane * 64;
    nb = nb < 0 ? 0 : (nb > 64 ? 64 : nb);
    keepw = (nb >= 64) ? ~0ull : ((nb > 0) ? ((1ull << nb) - 1ull) : 0ull);
  }
  bool ld = lane < 16;
  u64 cur[16], nxt[16];
#pragma unroll
  for (int r = 0; r < 16; r++) cur[r] = (ld && r < cnt) ? m[r] : 0ull;
  for (int g = 0; g < cnt; g += 16) {
#pragma unroll
    for (int r = 0; r < 16; r++) {
      int i = g + 16 + r;
      nxt[r] = (ld && i < cnt) ? m[i] : 0ull;
    }
#pragma unroll
    for (int r = 0; r < 16; r++) {
      int i = g + r;
      if (i < cnt) {
        u64 kw = __shfl(keepw, i >> 6);
        if ((kw >> (i & 63)) & 1ull) keepw &= ~cur[r];
      }
      cur[r] = nxt[r];
    }
  }
  if (lane < 16) keep_out[pair * 16 + lane] = keepw;
}

// ---------------------------------------------------------------------------
// kernel 5a: per pair: emit top-min(mb,kept) kept keys (scores_s is sorted,
// so the first set bits ARE the best). 1 wave per pair.
// key = (score_bits << 32) | ~(c*KNMS + k)
// ---------------------------------------------------------------------------
__global__ __launch_bounds__(64) void k_fa(const u64* __restrict__ keepm,
    const float* __restrict__ scores_s, u64* __restrict__ fa, int C, int mb) {
  int pair = blockIdx.x;
  int lane = threadIdx.x;
  int c = pair % C;
  u64 kw = (lane < 16) ? keepm[pair * 16 + lane] : 0ull;
  int pc = __popcll(kw);
  int scan = pc;
  for (int d = 1; d < 16; d <<= 1) {
    int o = __shfl_up(scan, d);
    if (lane >= d) scan += o;
  }
  int base = scan - pc;
  int total = __shfl(scan, 15);
  if (lane < 16) {
    u64 m = kw; int r = base;
    while (m && r < mb) {
      int bit = __ffsll((long long)m) - 1; m &= m - 1;
      int k = lane * 64 + bit;
      float s = scores_s[(size_t)pair * KP + k];
      fa[(size_t)pair * mb + r] =
          ((u64)__float_as_uint(s) << 32) | (unsigned)(~(unsigned)(c * KNMS + k));
      r++;
    }
  }
  int start = total < mb ? total : mb;
  for (int r = start + lane; r < mb; r += 64) fa[(size_t)pair * mb + r] = 0ull;
}

// ---------------------------------------------------------------------------
// kernel 5b: per batch: sort C*mb candidate keys desc, write outputs.
// ---------------------------------------------------------------------------
__global__ __launch_bounds__(1024) void k_fb(const u64* __restrict__ fa,
    const float* __restrict__ boxes_s, float* __restrict__ out,
    int B, int C, int mb) {
  int b = blockIdx.x, tid = threadIdx.x;
  __shared__ u64 cand[FBN];
  int nk = C * mb; if (nk > FBN) nk = FBN;
  const u64* src = fa + (size_t)b * C * mb;
  for (int i = tid; i < FBN; i += 1024) cand[i] = (i < nk) ? src[i] : 0ull;
  __syncthreads();
  bitonic_desc<FBN, 1024>(cand, tid);
  for (int k = tid; k < mb; k += 1024) {
    u64 key = cand[k];
    float4 bx = make_float4(0.f, 0.f, 0.f, 0.f);
    float sc = 0.f, cf = -1.f;
    if (key != 0ull) {
      sc = __uint_as_float((unsigned)(key >> 32));
      unsigned flat = ~(unsigned)key;
      int c = flat / KNMS;
      int kk = flat - c * KNMS;
      bx = ((const float4*)boxes_s)[(size_t)(b * C + c) * KP + kk];
      cf = (float)c;
    }
    size_t ro = (size_t)(b * mb + k) * 4;
    out[ro + 0] = bx.x; out[ro + 1] = bx.y; out[ro + 2] = bx.z; out[ro + 3] = bx.w;
    out[(size_t)B * mb * 4 + b * mb + k] = sc;
    out[(size_t)B * mb * 5 + b * mb + k] = cf;
  }
}

// ---------------------------------------------------------------------------
extern "C" void kernel_launch(void* const* d_in, const int* in_sizes, int n_in,
                              void* d_out, int out_size, void* d_ws, size_t ws_size,
                              hipStream_t stream) {
  const float* classification = (const float*)d_in[3];
  const float* tanch = (const float*)d_in[4];
  const float* thr_p = (const float*)d_in[5];

  int B = in_sizes[0] / (3 * 64 * 64);
  if (B <= 0) B = 4;
  long long BA = (long long)in_sizes[4] / 4;
  int A = (int)(BA / B);
  int C = (int)((long long)in_sizes[3] / BA);
  int NP = B * C;
  int mb = out_size / (B * 6);

  auto rsz = [](size_t x) { return (x + 255) & ~(size_t)255; };
  size_t clsT_bytes = rsz((size_t)NP * A * 4);
  size_t rest = rsz((size_t)NP * KP * 4)       // scores
              + rsz((size_t)NP * KP * 16)      // boxes
              + rsz((size_t)NP * KP * 4)       // areas
              + rsz((size_t)NP * 4)            // counts
              + rsz((size_t)NP * KP * 16 * 8)  // suppression matrix (+fa alias)
              + rsz((size_t)NP * 16 * 8);      // keep masks
  int use_t = (C <= 127 && ws_size >= rest + clsT_bytes) ? 1 : 0;

  size_t off = 0;
  auto take = [&](size_t bytes) {
    void* p = (char*)d_ws + off;
    off += rsz(bytes);
    return p;
  };
  float* clsT = nullptr;
  if (use_t) clsT = (float*)take((size_t)NP * A * 4);
  float* scores_s = (float*)take((size_t)NP * KP * 4);
  float* boxes_s  = (float*)take((size_t)NP * KP * 16);
  float* area_s   = (float*)take((size_t)NP * KP * 4);
  int*   cnt_s    = (int*)take((size_t)NP * 4);
  u64*   mat      = (u64*)take((size_t)NP * KP * 16 * 8);
  u64*   keepm    = (u64*)take((size_t)NP * 16 * 8);

  // fa aliases into mat (fa is written by k_fa AFTER k_scan's last mat read)
  u64* fa = (u64*)mat;

  if (use_t)
    k_transpose<<<dim3((A + 63) / 64, B), 256, 0, stream>>>(classification, clsT, A, C);
  const float* cl = use_t ? clsT : classification;
  k_select<<<NP, 1024, 0, stream>>>(cl, use_t, thr_p, tanch,
                                    scores_s, boxes_s, area_s, cnt_s, A, C);
  k_iou<<<dim3(NP, 16), 256, 0, stream>>>(boxes_s, area_s, cnt_s, mat);
  k_scan<<<NP, 64, 0, stream>>>(mat, cnt_s, keepm);
  k_fa<<<NP, 64, 0, stream>>>(keepm, scores_s, fa, C, mb);
  k_fb<<<B, 1024, 0, stream>>>(fa, boxes_s, (float*)d_out, B, C, mb);
}

// Round 7
// 541.075 us; speedup vs baseline: 1.3325x; 1.1936x over previous
//
#include <hip/hip_runtime.h>
#include <hip/hip_bf16.h>

typedef unsigned long long u64;

#define KNMS 1000      // MAX_BOX_PRE_NMS (hardcoded in reference)
#define KP   1024      // padded stride for per-pair arrays
#define CAP  4096      // candidate capacity per pair
#define NBIN 8192      // radix-select histogram bins (score bits >> 18)
#define SEG  240       // per-wave private segment in k_select (16*240=3840)
#define OVF  256       // overflow slots (3840+256 = CAP)
#define FSEL 1024      // k_fb compacted-candidate capacity
#define IOU_THR 0.5f

#define NEGINF __uint_as_float(0xFF800000u)

// ---------------------------------------------------------------------------
// helpers
// ---------------------------------------------------------------------------

// Find the histogram bin containing rank `rank` counting from the TOP.
__device__ __forceinline__ void find_cutoff(unsigned int* hist, int nbins,
    unsigned int* csum, int nthreads, int tid, unsigned int rank,
    unsigned int* s_bin, unsigned int* s_gt, unsigned int* s_total, int* s_all) {
  int chunk = nbins / nthreads;
  unsigned int cs = 0;
  int base = tid * chunk;
  for (int q = 0; q < chunk; q++) cs += hist[base + q];
  csum[tid] = cs;
  __syncthreads();
  if (tid == 0) {
    unsigned int total = 0;
    for (int ch = 0; ch < nthreads; ch++) total += csum[ch];
    *s_total = total;
    if (total <= rank) { *s_bin = 0u; *s_gt = 0u; *s_all = 1; }
    else {
      unsigned int acc = 0; int ch = nthreads - 1;
      while (acc + csum[ch] < rank) { acc += csum[ch]; ch--; }
      int bin = ch * chunk + chunk - 1;
      while (acc + hist[bin] < rank) { acc += hist[bin]; bin--; }
      *s_bin = (unsigned)bin; *s_gt = acc; *s_all = 0;
    }
  }
  __syncthreads();
}

// In-LDS bitonic sort, descending, 64-bit keys.
template<int N, int NT>
__device__ __forceinline__ void bitonic_desc(u64* a, int tid) {
  for (int k = 2; k <= N; k <<= 1) {
    for (int j = k >> 1; j > 0; j >>= 1) {
      for (int t = tid; t < N; t += NT) {
        int ixj = t ^ j;
        if (ixj > t) {
          u64 x = a[t], y = a[ixj];
          if (((t & k) == 0) ? (x < y) : (x > y)) { a[t] = y; a[ixj] = x; }
        }
      }
      __syncthreads();
    }
  }
}

// Bit-exact greedy-NMS predicate vs reference, PURE f32 (Sterbenz argument,
// see round-6 notes): fl(I/U) > 0.5  <=>  (I+I) - U > U * 2^-24  in f32.
__device__ __forceinline__ bool iou_gt(float4 bi, float ai, float4 bj, float aj) {
  float ltx = fmaxf(bi.x, bj.x), lty = fmaxf(bi.y, bj.y);
  float rbx = fminf(bi.z, bj.z), rby = fminf(bi.w, bj.w);
  float ww = fmaxf(rbx - ltx, 0.f), hh = fmaxf(rby - lty, 0.f);
  float inter = ww * hh;
  float uni = (ai + aj) - inter;
  float q = (inter + inter) - uni;
  float t = uni * 0x1p-24f;
  return q > t;
}

// ---------------------------------------------------------------------------
// kernel 1: transpose classification [B,A,C] -> [B,C,A]  (C <= 127)
// ---------------------------------------------------------------------------
__global__ __launch_bounds__(256) void k_transpose(const float* __restrict__ src0,
    float* __restrict__ dst0, int A, int C) {
  __shared__ float tile[64 * 129];
  int b = blockIdx.y;
  int a0 = blockIdx.x * 64;
  const float* src = src0 + (size_t)b * A * C;
  float* dst = dst0 + (size_t)b * A * C;
  int st = C + 1;
  for (int idx = threadIdx.x; idx < 64 * C; idx += 256) {
    int al = idx / C, c = idx - al * C;
    int a = a0 + al;
    tile[al * st + c] = (a < A) ? src[(size_t)a * C + c] : 0.f;
  }
  __syncthreads();
  for (int idx = threadIdx.x; idx < 64 * C; idx += 256) {
    int c = idx >> 6, al = idx & 63;
    int a = a0 + al;
    if (a < A) dst[(size_t)c * A + a] = tile[al * st + c];
  }
}

// ---------------------------------------------------------------------------
// kernel 2 (FUSED select): per pair: LDS hist -> cutoff -> compact -> sort.
// Round-7 fix: pass-2 staging uses WAVE-PRIVATE segments with a register-held
// running count (ballot prefix) -- no LDS atomic, no dependent shfl in the
// hot loop (round-6's per-ballot atomic+shfl chain was ~60-80us of serial
// latency). Rare overflow spills via one LDS atomic (capacity margin +23
// sigma for binomially-split takers; same total capacity CAP as before).
// key = (score_bits << 32) | ~anchor_index (stable: low index wins ties)
// ---------------------------------------------------------------------------
__global__ __launch_bounds__(1024) void k_select(const float* __restrict__ cls,
    int transposed, const float* __restrict__ thr_p,
    const float* __restrict__ tanch,
    float* __restrict__ scores_s, float* __restrict__ boxes_s,
    float* __restrict__ area_s, int* __restrict__ cnt_s, int A, int C) {
  int pair = blockIdx.x, tid = threadIdx.x;
  int b = pair / C, c = pair - b * C;
  const float* col; int str;
  if (transposed) { col = cls + (size_t)pair * A; str = 1; }
  else            { col = cls + (size_t)b * A * C + c; str = C; }
  float thr = *thr_p;

  __shared__ union { unsigned int hist[NBIN]; u64 cand[CAP]; } sh;
  __shared__ unsigned int csum[1024];
  __shared__ unsigned int s_b1, s_gt, s_tot;
  __shared__ int s_all, s_ovf;

  for (int i = tid; i < NBIN; i += 1024) sh.hist[i] = 0u;
  __syncthreads();

  bool vec = (str == 1) && ((A & 3) == 0);
  if (vec) {
    const float4* col4 = (const float4*)col;
    int A4 = A >> 2;
    for (int i = tid; i < A4; i += 1024) {
      float4 v = col4[i];
      float vv[4] = {v.x, v.y, v.z, v.w};
#pragma unroll
      for (int q = 0; q < 4; q++)
        if (vv[q] > thr) atomicAdd(&sh.hist[__float_as_uint(vv[q]) >> 18], 1u);
    }
  } else {
    for (int a = tid; a < A; a += 1024) {
      float sv = col[(size_t)a * str];
      if (sv > thr) atomicAdd(&sh.hist[__float_as_uint(sv) >> 18], 1u);
    }
  }
  __syncthreads();
  find_cutoff(sh.hist, NBIN, csum, 1024, tid, KNMS, &s_b1, &s_gt, &s_tot, &s_all);
  unsigned b1 = s_all ? 0u : s_b1;
  unsigned tot = s_tot;
  for (int t = tid; t < CAP; t += 1024) sh.cand[t] = 0ull;
  if (tid == 0) s_ovf = 0;
  __syncthreads();

  int lane = tid & 63, wv = tid >> 6;
  u64* seg = sh.cand + wv * SEG;
  int nloc = 0;                     // wave-uniform running count (register)
  u64 lmask = (1ull << lane) - 1ull;
  auto stage = [&](u64 key, bool take) {
    u64 m = __ballot(take);
    if (!m) return;
    if (take) {
      int pos = nloc + (int)__popcll(m & lmask);
      if (pos < SEG) seg[pos] = key;
      else {                        // ~never: +23 sigma margin
        int p2 = atomicAdd(&s_ovf, 1);
        if (p2 < OVF) sh.cand[16 * SEG + p2] = key;
      }
    }
    nloc += (int)__popcll(m);
  };

  if (vec) {
    const float4* col4 = (const float4*)col;
    int A4 = A >> 2;
    for (int i = tid; i < A4; i += 1024) {
      float4 v = col4[i];
      float vv[4] = {v.x, v.y, v.z, v.w};
#pragma unroll
      for (int q = 0; q < 4; q++) {
        float sv = vv[q];
        unsigned bits = __float_as_uint(sv);
        bool take = (sv > thr) && ((bits >> 18) >= b1);
        u64 key = ((u64)bits << 32) | (unsigned)(~(unsigned)(i * 4 + q));
        stage(key, take);
      }
    }
  } else {
    for (int a = tid; a < A; a += 1024) {
      float sv = col[(size_t)a * str];
      unsigned bits = __float_as_uint(sv);
      bool take = (sv > thr) && ((bits >> 18) >= b1);
      u64 key = ((u64)bits << 32) | (unsigned)(~(unsigned)a);
      stage(key, take);
    }
  }
  __syncthreads();

  bitonic_desc<CAP, 1024>(sh.cand, tid);

  int n_valid = (int)tot < KNMS ? (int)tot : KNMS;
  for (int k = tid; k < KNMS; k += 1024) {
    u64 key = sh.cand[k];
    float sc; float4 bx; float ar;
    if (k < n_valid && key != 0ull) {
      sc = __uint_as_float((unsigned)(key >> 32));
      unsigned a = ~(unsigned)key;
      bx = ((const float4*)tanch)[(size_t)b * A + a];
      ar = (bx.z - bx.x) * (bx.w - bx.y);
    } else {
      sc = NEGINF; bx = make_float4(0.f, 0.f, 0.f, 0.f); ar = 0.f;
    }
    scores_s[(size_t)pair * KP + k] = sc;
    ((float4*)boxes_s)[(size_t)pair * KP + k] = bx;
    area_s[(size_t)pair * KP + k] = ar;
  }
  if (tid == 0) cnt_s[pair] = n_valid;
}

// ---------------------------------------------------------------------------
// kernel 3: suppression matrix, transposed layout mat[pair][w][i].
// Round-7: i-loop split at the diagonal -- below-diagonal rows need neither
// the j>i nor the jok compare (jok folded into uniform jmask on the word).
// ---------------------------------------------------------------------------
__global__ __launch_bounds__(256) void k_iou(const float* __restrict__ boxes_s,
    const float* __restrict__ area_s, const int* __restrict__ cnt_s,
    u64* __restrict__ mat) {
  int pair = blockIdx.x, w = blockIdx.y;
  int cnt = cnt_s[pair];
  int lim = (w + 1) * 64; if (lim > KNMS) lim = KNMS;
  __shared__ float4 sbox[KNMS];
  __shared__ float sarea[KNMS];
  __shared__ u64 rowm[KP];
  for (int i = threadIdx.x; i < lim; i += 256) {
    sbox[i] = ((const float4*)boxes_s)[(size_t)pair * KP + i];
    sarea[i] = area_s[(size_t)pair * KP + i];
  }
  for (int i = threadIdx.x; i < KP; i += 256) rowm[i] = 0ull;
  __syncthreads();
  int lane = threadIdx.x & 63, wv = threadIdx.x >> 6;
  int dstart = w * 64;
  int j = dstart + lane;
  float4 bj = (j < lim) ? sbox[j] : make_float4(0.f, 0.f, 0.f, 0.f);
  float aj = (j < lim) ? sarea[j] : 0.f;
  int nj = KNMS - dstart;
  u64 jmask = (nj >= 64) ? ~0ull : ((1ull << nj) - 1ull);
  // part 1: strictly below the diagonal chunk (j > i guaranteed)
  int lim1 = cnt < dstart ? cnt : dstart;
  for (int i = wv; i < lim1; i += 4) {
    float4 bi = sbox[i]; float ai = sarea[i];
    u64 word = __ballot(iou_gt(bi, ai, bj, aj)) & jmask;
    if (lane == 0) rowm[i] = word;
  }
  // part 2: diagonal chunk (need lane > i-dstart)
  int rowLim = cnt < (dstart + 63) ? cnt : (dstart + 63);
  for (int i = dstart + wv; i < rowLim; i += 4) {
    int il = i - dstart;
    float4 bi = sbox[i]; float ai = sarea[i];
    u64 word = __ballot((lane > il) && iou_gt(bi, ai, bj, aj)) & jmask;
    if (lane == 0) rowm[i] = word;
  }
  __syncthreads();
  u64* dst = mat + ((size_t)pair * 16 + w) * KP;
  for (int t = threadIdx.x; t < cnt; t += 256) dst[t] = rowm[t];
}

// ---------------------------------------------------------------------------
// kernel 4: serial greedy scan. 1 wave per pair; lanes 0..15 own keep-words.
// ---------------------------------------------------------------------------
__global__ __launch_bounds__(64) void k_scan(const u64* __restrict__ mat,
    const int* __restrict__ cnt_s, u64* __restrict__ keep_out) {
  int pair = blockIdx.x;
  int lane = threadIdx.x;
  int cnt = cnt_s[pair];
  const u64* m = mat + (size_t)pair * KP * 16 + (size_t)lane * KP;
  u64 keepw = 0ull;
  if (lane < 16) {
    int nb = cnt - lane * 64;
    nb = nb < 0 ? 0 : (nb > 64 ? 64 : nb);
    keepw = (nb >= 64) ? ~0ull : ((nb > 0) ? ((1ull << nb) - 1ull) : 0ull);
  }
  bool ld = lane < 16;
  u64 cur[16], nxt[16];
#pragma unroll
  for (int r = 0; r < 16; r++) cur[r] = (ld && r < cnt) ? m[r] : 0ull;
  for (int g = 0; g < cnt; g += 16) {
#pragma unroll
    for (int r = 0; r < 16; r++) {
      int i = g + 16 + r;
      nxt[r] = (ld && i < cnt) ? m[i] : 0ull;
    }
#pragma unroll
    for (int r = 0; r < 16; r++) {
      int i = g + r;
      if (i < cnt) {
        u64 kw = __shfl(keepw, i >> 6);
        if ((kw >> (i & 63)) & 1ull) keepw &= ~cur[r];
      }
      cur[r] = nxt[r];
    }
  }
  if (lane < 16) keep_out[pair * 16 + lane] = keepw;
}

// ---------------------------------------------------------------------------
// kernel 5a: per pair: emit top-min(mb,kept) kept keys. 1 wave per pair.
// key = (score_bits << 32) | ~(c*KNMS + k)
// ---------------------------------------------------------------------------
__global__ __launch_bounds__(64) void k_fa(const u64* __restrict__ keepm,
    const float* __restrict__ scores_s, u64* __restrict__ fa, int C, int mb) {
  int pair = blockIdx.x;
  int lane = threadIdx.x;
  int c = pair % C;
  u64 kw = (lane < 16) ? keepm[pair * 16 + lane] : 0ull;
  int pc = __popcll(kw);
  int scan = pc;
  for (int d = 1; d < 16; d <<= 1) {
    int o = __shfl_up(scan, d);
    if (lane >= d) scan += o;
  }
  int base = scan - pc;
  int total = __shfl(scan, 15);
  if (lane < 16) {
    u64 m = kw; int r = base;
    while (m && r < mb) {
      int bit = __ffsll((long long)m) - 1; m &= m - 1;
      int k = lane * 64 + bit;
      float s = scores_s[(size_t)pair * KP + k];
      fa[(size_t)pair * mb + r] =
          ((u64)__float_as_uint(s) << 32) | (unsigned)(~(unsigned)(c * KNMS + k));
      r++;
    }
  }
  int start = total < mb ? total : mb;
  for (int r = start + lane; r < mb; r += 64) fa[(size_t)pair * mb + r] = 0ull;
}

// ---------------------------------------------------------------------------
// kernel 5b: per batch: top-mb of C*mb keys via 2-level radix select +
// small bitonic (replaces the 91-step 8192-key bitonic, ~40us -> ~8us).
// Level-2 is needed because post-NMS scores cluster into 1-2 coarse bins.
// Capacity FSEL=1024 >> takers (= <=mb + boundary-sub-bin, ~305 for this
// workload; >1024 would need ~900 exact score-bit ties at the boundary).
// ---------------------------------------------------------------------------
__global__ __launch_bounds__(1024) void k_fb(const u64* __restrict__ fa,
    const float* __restrict__ boxes_s, float* __restrict__ out,
    int B, int C, int mb) {
  int b = blockIdx.x, tid = threadIdx.x;
  __shared__ union { unsigned int hist[NBIN]; u64 cand[FSEL]; } sh;
  __shared__ unsigned int csum[1024];
  __shared__ unsigned int s_b1, s_gt, s_tot, s_b2, s_gt2, s_tot2;
  __shared__ int s_all, s_all2, s_n, s_lvl2;
  int nk = C * mb;
  const u64* src = fa + (size_t)b * nk;

  for (int i = tid; i < NBIN; i += 1024) sh.hist[i] = 0u;
  __syncthreads();
  for (int i = tid; i < nk; i += 1024) {
    u64 key = src[i];
    if (key) atomicAdd(&sh.hist[(unsigned)(key >> 32) >> 18], 1u);
  }
  __syncthreads();
  find_cutoff(sh.hist, NBIN, csum, 1024, tid, (unsigned)mb, &s_b1, &s_gt, &s_tot, &s_all);
  unsigned b1 = s_all ? 0u : s_b1;
  unsigned gt1 = s_gt, tot = s_tot;
  int all1 = s_all;
  unsigned m1 = sh.hist[b1];
  if (tid == 0) s_lvl2 = (!all1 && gt1 + m1 > FSEL) ? 1 : 0;
  __syncthreads();
  int lvl2 = s_lvl2;
  unsigned b2 = 0; int all2 = 1;
  if (lvl2) {
    for (int i = tid; i < 2048; i += 1024) sh.hist[i] = 0u;
    __syncthreads();
    for (int i = tid; i < nk; i += 1024) {
      u64 key = src[i];
      if (key) {
        unsigned bits = (unsigned)(key >> 32);
        if ((bits >> 18) == b1) atomicAdd(&sh.hist[(bits >> 7) & 2047u], 1u);
      }
    }
    __syncthreads();
    find_cutoff(sh.hist, 2048, csum, 1024, tid, (unsigned)mb - gt1,
                &s_b2, &s_gt2, &s_tot2, &s_all2);
    all2 = s_all2;
    b2 = all2 ? 0u : s_b2;
  }
  for (int t = tid; t < FSEL; t += 1024) sh.cand[t] = 0ull;
  if (tid == 0) s_n = 0;
  __syncthreads();
  for (int i = tid; i < nk; i += 1024) {
    u64 key = src[i];
    if (!key) continue;
    unsigned bits = (unsigned)(key >> 32);
    unsigned bin = bits >> 18;
    bool take = all1 || bin > b1 ||
                (bin == b1 && (!lvl2 || all2 || ((bits >> 7) & 2047u) >= b2));
    if (take) {
      int pos = atomicAdd(&s_n, 1);          // <= ~305 takes: trivial cost
      if (pos < FSEL) sh.cand[pos] = key;
    }
  }
  __syncthreads();
  bitonic_desc<FSEL, 1024>(sh.cand, tid);

  int n_out = (int)tot < mb ? (int)tot : mb;
  for (int k = tid; k < mb; k += 1024) {
    u64 key = sh.cand[k];
    float4 bx = make_float4(0.f, 0.f, 0.f, 0.f);
    float sc = 0.f, cf = -1.f;
    if (k < n_out && key != 0ull) {
      sc = __uint_as_float((unsigned)(key >> 32));
      unsigned flat = ~(unsigned)key;
      int c = flat / KNMS;
      int kk = flat - c * KNMS;
      bx = ((const float4*)boxes_s)[(size_t)(b * C + c) * KP + kk];
      cf = (float)c;
    }
    size_t ro = (size_t)(b * mb + k) * 4;
    out[ro + 0] = bx.x; out[ro + 1] = bx.y; out[ro + 2] = bx.z; out[ro + 3] = bx.w;
    out[(size_t)B * mb * 4 + b * mb + k] = sc;
    out[(size_t)B * mb * 5 + b * mb + k] = cf;
  }
}

// ---------------------------------------------------------------------------
extern "C" void kernel_launch(void* const* d_in, const int* in_sizes, int n_in,
                              void* d_out, int out_size, void* d_ws, size_t ws_size,
                              hipStream_t stream) {
  const float* classification = (const float*)d_in[3];
  const float* tanch = (const float*)d_in[4];
  const float* thr_p = (const float*)d_in[5];

  int B = in_sizes[0] / (3 * 64 * 64);
  if (B <= 0) B = 4;
  long long BA = (long long)in_sizes[4] / 4;
  int A = (int)(BA / B);
  int C = (int)((long long)in_sizes[3] / BA);
  int NP = B * C;
  int mb = out_size / (B * 6);

  auto rsz = [](size_t x) { return (x + 255) & ~(size_t)255; };
  size_t clsT_bytes = rsz((size_t)NP * A * 4);
  size_t rest = rsz((size_t)NP * KP * 4)       // scores
              + rsz((size_t)NP * KP * 16)      // boxes
              + rsz((size_t)NP * KP * 4)       // areas
              + rsz((size_t)NP * 4)            // counts
              + rsz((size_t)NP * KP * 16 * 8)  // suppression matrix (+fa alias)
              + rsz((size_t)NP * 16 * 8);      // keep masks
  int use_t = (C <= 127 && ws_size >= rest + clsT_bytes) ? 1 : 0;

  size_t off = 0;
  auto take = [&](size_t bytes) {
    void* p = (char*)d_ws + off;
    off += rsz(bytes);
    return p;
  };
  float* clsT = nullptr;
  if (use_t) clsT = (float*)take((size_t)NP * A * 4);
  float* scores_s = (float*)take((size_t)NP * KP * 4);
  float* boxes_s  = (float*)take((size_t)NP * KP * 16);
  float* area_s   = (float*)take((size_t)NP * KP * 4);
  int*   cnt_s    = (int*)take((size_t)NP * 4);
  u64*   mat      = (u64*)take((size_t)NP * KP * 16 * 8);
  u64*   keepm    = (u64*)take((size_t)NP * 16 * 8);

  // fa aliases into mat (fa is written by k_fa AFTER k_scan's last mat read)
  u64* fa = (u64*)mat;

  if (use_t)
    k_transpose<<<dim3((A + 63) / 64, B), 256, 0, stream>>>(classification, clsT, A, C);
  const float* cl = use_t ? clsT : classification;
  k_select<<<NP, 1024, 0, stream>>>(cl, use_t, thr_p, tanch,
                                    scores_s, boxes_s, area_s, cnt_s, A, C);
  k_iou<<<dim3(NP, 16), 256, 0, stream>>>(boxes_s, area_s, cnt_s, mat);
  k_scan<<<NP, 64, 0, stream>>>(mat, cnt_s, keepm);
  k_fa<<<NP, 64, 0, stream>>>(keepm, scores_s, fa, C, mb);
  k_fb<<<B, 1024, 0, stream>>>(fa, boxes_s, (float*)d_out, B, C, mb);
}

// Round 8
// 465.355 us; speedup vs baseline: 1.5493x; 1.1627x over previous
//
#include <hip/hip_runtime.h>
#include <hip/hip_bf16.h>

typedef unsigned long long u64;

#define KNMS 1000      // MAX_BOX_PRE_NMS (hardcoded in reference)
#define KP   1024      // padded stride for per-pair arrays
#define CAP  4096      // candidate capacity per pair
#define NBIN 8192      // radix-select histogram bins (score bits >> 18)
#define SLICES 320     // k_selA: A-dim slices per batch
#define SCAP 32        // per (slice,class) key capacity (mean ~10, +7 sigma)
#define SLOTS (SLICES*SCAP)
#define CMAX 128       // k_sample/k_selA support C <= CMAX (else fallback path)
#define FSEL 1024      // k_fb compacted-candidate capacity
#define IOU_THR 0.5f

#define NEGINF __uint_as_float(0xFF800000u)

// ---------------------------------------------------------------------------
// helpers
// ---------------------------------------------------------------------------

// Find the histogram bin containing rank `rank` counting from the TOP.
__device__ __forceinline__ void find_cutoff(unsigned int* hist, int nbins,
    unsigned int* csum, int nthreads, int tid, unsigned int rank,
    unsigned int* s_bin, unsigned int* s_gt, unsigned int* s_total, int* s_all) {
  int chunk = nbins / nthreads;
  unsigned int cs = 0;
  int base = tid * chunk;
  for (int q = 0; q < chunk; q++) cs += hist[base + q];
  csum[tid] = cs;
  __syncthreads();
  if (tid == 0) {
    unsigned int total = 0;
    for (int ch = 0; ch < nthreads; ch++) total += csum[ch];
    *s_total = total;
    if (total <= rank) { *s_bin = 0u; *s_gt = 0u; *s_all = 1; }
    else {
      unsigned int acc = 0; int ch = nthreads - 1;
      while (acc + csum[ch] < rank) { acc += csum[ch]; ch--; }
      int bin = ch * chunk + chunk - 1;
      while (acc + hist[bin] < rank) { acc += hist[bin]; bin--; }
      *s_bin = (unsigned)bin; *s_gt = acc; *s_all = 0;
    }
  }
  __syncthreads();
}

// In-LDS bitonic sort, descending, 64-bit keys.
template<int N, int NT>
__device__ __forceinline__ void bitonic_desc(u64* a, int tid) {
  for (int k = 2; k <= N; k <<= 1) {
    for (int j = k >> 1; j > 0; j >>= 1) {
      for (int t = tid; t < N; t += NT) {
        int ixj = t ^ j;
        if (ixj > t) {
          u64 x = a[t], y = a[ixj];
          if (((t & k) == 0) ? (x < y) : (x > y)) { a[t] = y; a[ixj] = x; }
        }
      }
      __syncthreads();
    }
  }
}

// Bit-exact greedy-NMS predicate vs reference, PURE f32 (Sterbenz argument,
// see round-6 notes): fl(I/U) > 0.5  <=>  (I+I) - U > U * 2^-24  in f32.
__device__ __forceinline__ bool iou_gt(float4 bi, float ai, float4 bj, float aj) {
  float ltx = fmaxf(bi.x, bj.x), lty = fmaxf(bi.y, bj.y);
  float rbx = fminf(bi.z, bj.z), rby = fminf(bi.w, bj.w);
  float ww = fmaxf(rbx - ltx, 0.f), hh = fmaxf(rby - lty, 0.f);
  float inter = ww * hh;
  float uni = (ai + aj) - inter;
  float q = (inter + inter) - uni;
  float t = uni * 0x1p-24f;
  return q > t;
}

// ---------------------------------------------------------------------------
// kernel S0: per batch, sample 4096 anchor-rows (coalesced, original layout),
// build per-class 64-bin hists RELATIVE to thr's coarse bin, and emit a
// per-pair bit-cutoff (bin number; 0 = take-all-above-thr).
// Target capture: ~1500 above the cut bin (+ boundary bin ~1500) => ~3000 of
// CAP=4096. Any mis-estimate is caught by k_selB's exact fallback.
// ---------------------------------------------------------------------------
__global__ __launch_bounds__(1024) void k_sample(const float* __restrict__ cls,
    const float* __restrict__ thr_p, unsigned* __restrict__ gcut, int A, int C) {
  int b = blockIdx.x, tid = threadIdx.x;
  __shared__ unsigned hist[CMAX * 64];
  float thr = *thr_p;
  unsigned base_bin = __float_as_uint(thr) >> 18;
  for (int i = tid; i < C * 64; i += 1024) hist[i] = 0u;
  __syncthreads();
  const float* src = cls + (size_t)b * A * C;
  const int NS = 4096;
  if ((C & 3) == 0) {
    int C4 = C >> 2;
    const float4* s4 = (const float4*)src;
    int tot4 = NS * C4;
    for (int idx = tid; idx < tot4; idx += 1024) {
      int s = idx / C4, c4 = idx - s * C4;
      int a = (int)(((long long)s * A) >> 12);
      float4 v = s4[(size_t)a * C4 + c4];
      float vv[4] = {v.x, v.y, v.z, v.w};
#pragma unroll
      for (int q = 0; q < 4; q++) {
        float sv = vv[q];
        if (sv > thr) {
          unsigned rel = (__float_as_uint(sv) >> 18) - base_bin;
          if (rel > 63u) rel = 63u;
          atomicAdd(&hist[(c4 * 4 + q) * 64 + rel], 1u);
        }
      }
    }
  } else {
    int tot = NS * C;
    for (int idx = tid; idx < tot; idx += 1024) {
      int s = idx / C, c = idx - s * C;
      int a = (int)(((long long)s * A) >> 12);
      float sv = src[(size_t)a * C + c];
      if (sv > thr) {
        unsigned rel = (__float_as_uint(sv) >> 18) - base_bin;
        if (rel > 63u) rel = 63u;
        atomicAdd(&hist[c * 64 + rel], 1u);
      }
    }
  }
  __syncthreads();
  if (tid < C) {
    int ns = NS < A ? NS : A;
    long long r = (1500LL * ns) / A; if (r < 1) r = 1;
    unsigned acc = 0; int bin = -1;
    for (int rb = 63; rb >= 0; --rb) {
      acc += hist[tid * 64 + rb];
      if (acc >= (unsigned)r) { bin = rb; break; }
    }
    gcut[b * C + tid] = (bin < 0) ? 0u : (base_bin + (unsigned)bin);
  }
}

// ---------------------------------------------------------------------------
// kernel S1: per (slice, batch): single streaming pass over the ORIGINAL
// [B,A,C] layout (coalesced float4, no transpose). Elements passing
// (s > thr && coarse_bin >= cut[c]) are staged in per-class LDS lists
// (sparse LDS atomics, ~10/class) and dumped to STATICALLY-assigned gcand
// slots -- no global returning atomics anywhere. Per-cell overflow (>SCAP,
// ~7-sigma out) sets the pair's fallback flag.
// key = (score_bits << 32) | ~anchor_index (stable: low index wins ties)
// ---------------------------------------------------------------------------
__global__ __launch_bounds__(512) void k_selA(const float* __restrict__ cls,
    const float* __restrict__ thr_p, const unsigned* __restrict__ gcut,
    u64* __restrict__ gcand, unsigned* __restrict__ gpc,
    unsigned* __restrict__ gflag, int A, int C) {
  int slice = blockIdx.x, b = blockIdx.y, tid = threadIdx.x;
  __shared__ u64 stage[CMAX * SCAP];
  __shared__ unsigned pcnt[CMAX];
  __shared__ unsigned lcut[CMAX];
  float thr = *thr_p;
  for (int i = tid; i < C; i += 512) { pcnt[i] = 0u; lcut[i] = gcut[b * C + i]; }
  __syncthreads();
  int ANC = (A + SLICES - 1) / SLICES;
  int a0 = slice * ANC, a1 = min(A, a0 + ANC);
  if (a0 < a1) {
    const float* src = cls + (size_t)b * A * C;
    if ((C & 3) == 0) {
      int C4 = C >> 2;
      const float4* s4 = (const float4*)src + (size_t)a0 * C4;
      int n4 = (a1 - a0) * C4;
      for (int t = tid; t < n4; t += 512) {
        float4 v = s4[t];
        int ar = t / C4, c4 = t - ar * C4;
        int a = a0 + ar;
        float vv[4] = {v.x, v.y, v.z, v.w};
#pragma unroll
        for (int q = 0; q < 4; q++) {
          float sv = vv[q];
          unsigned bits = __float_as_uint(sv);
          int c = c4 * 4 + q;
          if (sv > thr && (bits >> 18) >= lcut[c]) {
            unsigned pos = atomicAdd(&pcnt[c], 1u);
            if (pos < SCAP)
              stage[c * SCAP + pos] = ((u64)bits << 32) | (unsigned)(~(unsigned)a);
          }
        }
      }
    } else {
      const float* sp = src + (size_t)a0 * C;
      int n = (a1 - a0) * C;
      for (int t = tid; t < n; t += 512) {
        float sv = sp[t];
        int ar = t / C, c = t - ar * C;
        int a = a0 + ar;
        unsigned bits = __float_as_uint(sv);
        if (sv > thr && (bits >> 18) >= lcut[c]) {
          unsigned pos = atomicAdd(&pcnt[c], 1u);
          if (pos < SCAP)
            stage[c * SCAP + pos] = ((u64)bits << 32) | (unsigned)(~(unsigned)a);
        }
      }
    }
  }
  __syncthreads();
  for (int idx = tid; idx < C * SCAP; idx += 512) {
    int c = idx >> 5, j = idx & (SCAP - 1);
    unsigned cnt = pcnt[c]; if (cnt > SCAP) cnt = SCAP;
    if ((unsigned)j < cnt)
      gcand[(size_t)(b * C + c) * SLOTS + slice * SCAP + j] = stage[idx];
  }
  for (int c = tid; c < C; c += 512) {
    unsigned cnt = pcnt[c];
    if (cnt > SCAP) { atomicOr(&gflag[b * C + c], 1u); cnt = SCAP; }
    gpc[(size_t)(b * C + c) * SLICES + slice] = cnt;
  }
}

// ---------------------------------------------------------------------------
// kernel S2: per pair: prefix-sum slice counts, gather keys into LDS, bitonic
// sort, gather boxes, write sorted per-pair arrays. If capture is invalid
// (overflow flag / >CAP / sampled-mode with <KNMS), run the EXACT per-pair
// fallback (hist + cutoff + compact from the strided original layout) --
// rare, deterministic, correct for any data.
// ---------------------------------------------------------------------------
__global__ __launch_bounds__(1024) void k_selB(const u64* __restrict__ gcand,
    const unsigned* __restrict__ gpc, const unsigned* __restrict__ gcut,
    const unsigned* __restrict__ gflag, const float* __restrict__ cls,
    const float* __restrict__ thr_p, const float* __restrict__ tanch,
    float* __restrict__ scores_s, float* __restrict__ boxes_s,
    float* __restrict__ area_s, int* __restrict__ cnt_s, int A, int C) {
  int pair = blockIdx.x, tid = threadIdx.x;
  int b = pair / C, c = pair - b * C;
  __shared__ union { unsigned hist[NBIN]; u64 cand[CAP]; } sh;
  __shared__ unsigned cnts[SLICES];
  __shared__ unsigned pre[SLICES];
  __shared__ unsigned csum[1024];
  __shared__ unsigned s_b1, s_gt, s_tot;
  __shared__ int s_all, s_ovf;

  unsigned flag = gflag[pair];
  for (int i = tid; i < SLICES; i += 1024) {
    unsigned v = gpc[(size_t)pair * SLICES + i];
    cnts[i] = v; pre[i] = v;
  }
  __syncthreads();
  for (int d = 1; d < SLICES; d <<= 1) {      // Hillis-Steele inclusive scan
    unsigned v = 0;
    if (tid < SLICES && tid >= d) v = pre[tid - d];
    __syncthreads();
    if (tid < SLICES && tid >= d) pre[tid] += v;
    __syncthreads();
  }
  unsigned total = pre[SLICES - 1];
  bool mode_sampled = (gcut[pair] != 0u);
  bool bad = (flag != 0u) || (total > CAP) ||
             (mode_sampled && total < (unsigned)KNMS);
  unsigned n_valid_u;
  if (!bad) {
    for (int t = tid; t < CAP; t += 1024) sh.cand[t] = 0ull;
    __syncthreads();
    const u64* src = gcand + (size_t)pair * SLOTS;
    for (int idx = tid; idx < SLOTS; idx += 1024) {
      int s = idx >> 5, j = idx & (SCAP - 1);
      if ((unsigned)j < cnts[s]) sh.cand[(pre[s] - cnts[s]) + j] = src[idx];
    }
    __syncthreads();
    n_valid_u = total < (unsigned)KNMS ? total : (unsigned)KNMS;
  } else {
    // ---- exact fallback (strided reads; rare) ----
    const float* col = cls + (size_t)b * A * C + c;
    float thr = *thr_p;
    for (int i = tid; i < NBIN; i += 1024) sh.hist[i] = 0u;
    __syncthreads();
    for (int a = tid; a < A; a += 1024) {
      float sv = col[(size_t)a * C];
      if (sv > thr) atomicAdd(&sh.hist[__float_as_uint(sv) >> 18], 1u);
    }
    __syncthreads();
    find_cutoff(sh.hist, NBIN, csum, 1024, tid, KNMS, &s_b1, &s_gt, &s_tot, &s_all);
    unsigned b1 = s_all ? 0u : s_b1;
    unsigned tot = s_tot;
    __syncthreads();
    for (int t = tid; t < CAP; t += 1024) sh.cand[t] = 0ull;
    if (tid == 0) s_ovf = 0;
    __syncthreads();
    int lane = tid & 63, wv = tid >> 6;     // 16 waves, SEG=240, OVF=256
    u64* seg = sh.cand + wv * 240;
    int nloc = 0;
    u64 lmask = (1ull << lane) - 1ull;
    for (int a = tid; a < A; a += 1024) {
      float sv = col[(size_t)a * C];
      unsigned bits = __float_as_uint(sv);
      bool take = (sv > thr) && ((bits >> 18) >= b1);
      u64 m = __ballot(take);
      if (m) {
        if (take) {
          u64 key = ((u64)bits << 32) | (unsigned)(~(unsigned)a);
          int pos = nloc + (int)__popcll(m & lmask);
          if (pos < 240) seg[pos] = key;
          else { int p2 = atomicAdd(&s_ovf, 1); if (p2 < 256) sh.cand[16 * 240 + p2] = key; }
        }
        nloc += (int)__popcll(m);
      }
    }
    __syncthreads();
    n_valid_u = tot < (unsigned)KNMS ? tot : (unsigned)KNMS;
  }

  bitonic_desc<CAP, 1024>(sh.cand, tid);

  int n_valid = (int)n_valid_u;
  for (int k = tid; k < KNMS; k += 1024) {
    u64 key = sh.cand[k];
    float sc; float4 bx; float ar;
    if (k < n_valid && key != 0ull) {
      sc = __uint_as_float((unsigned)(key >> 32));
      unsigned a = ~(unsigned)key;
      bx = ((const float4*)tanch)[(size_t)b * A + a];
      ar = (bx.z - bx.x) * (bx.w - bx.y);
    } else {
      sc = NEGINF; bx = make_float4(0.f, 0.f, 0.f, 0.f); ar = 0.f;
    }
    scores_s[(size_t)pair * KP + k] = sc;
    ((float4*)boxes_s)[(size_t)pair * KP + k] = bx;
    area_s[(size_t)pair * KP + k] = ar;
  }
  if (tid == 0) cnt_s[pair] = n_valid;
}

// ---------------------------------------------------------------------------
// kernel 3: suppression matrix, transposed layout mat[pair][w][i], diagonal-
// split i-loop, LDS-accumulated coalesced strip dump (round-7 version).
// ---------------------------------------------------------------------------
__global__ __launch_bounds__(256) void k_iou(const float* __restrict__ boxes_s,
    const float* __restrict__ area_s, const int* __restrict__ cnt_s,
    u64* __restrict__ mat) {
  int pair = blockIdx.x, w = blockIdx.y;
  int cnt = cnt_s[pair];
  int lim = (w + 1) * 64; if (lim > KNMS) lim = KNMS;
  __shared__ float4 sbox[KNMS];
  __shared__ float sarea[KNMS];
  __shared__ u64 rowm[KP];
  for (int i = threadIdx.x; i < lim; i += 256) {
    sbox[i] = ((const float4*)boxes_s)[(size_t)pair * KP + i];
    sarea[i] = area_s[(size_t)pair * KP + i];
  }
  for (int i = threadIdx.x; i < KP; i += 256) rowm[i] = 0ull;
  __syncthreads();
  int lane = threadIdx.x & 63, wv = threadIdx.x >> 6;
  int dstart = w * 64;
  int j = dstart + lane;
  float4 bj = (j < lim) ? sbox[j] : make_float4(0.f, 0.f, 0.f, 0.f);
  float aj = (j < lim) ? sarea[j] : 0.f;
  int nj = KNMS - dstart;
  u64 jmask = (nj >= 64) ? ~0ull : ((1ull << nj) - 1ull);
  int lim1 = cnt < dstart ? cnt : dstart;
  for (int i = wv; i < lim1; i += 4) {
    float4 bi = sbox[i]; float ai = sarea[i];
    u64 word = __ballot(iou_gt(bi, ai, bj, aj)) & jmask;
    if (lane == 0) rowm[i] = word;
  }
  int rowLim = cnt < (dstart + 63) ? cnt : (dstart + 63);
  for (int i = dstart + wv; i < rowLim; i += 4) {
    int il = i - dstart;
    float4 bi = sbox[i]; float ai = sarea[i];
    u64 word = __ballot((lane > il) && iou_gt(bi, ai, bj, aj)) & jmask;
    if (lane == 0) rowm[i] = word;
  }
  __syncthreads();
  u64* dst = mat + ((size_t)pair * 16 + w) * KP;
  for (int t = threadIdx.x; t < cnt; t += 256) dst[t] = rowm[t];
}

// ---------------------------------------------------------------------------
// kernel 4: serial greedy scan. 1 wave per pair; lanes 0..15 own keep-words.
// ---------------------------------------------------------------------------
__global__ __launch_bounds__(64) void k_scan(const u64* __restrict__ mat,
    const int* __restrict__ cnt_s, u64* __restrict__ keep_out) {
  int pair = blockIdx.x;
  int lane = threadIdx.x;
  int cnt = cnt_s[pair];
  const u64* m = mat + (size_t)pair * KP * 16 + (size_t)lane * KP;
  u64 keepw = 0ull;
  if (lane < 16) {
    int nb = cnt - lane * 64;
    nb = nb < 0 ? 0 : (nb > 64 ? 64 : nb);
    keepw = (nb >= 64) ? ~0ull : ((nb > 0) ? ((1ull << nb) - 1ull) : 0ull);
  }
  bool ld = lane < 16;
  u64 cur[16], nxt[16];
#pragma unroll
  for (int r = 0; r < 16; r++) cur[r] = (ld && r < cnt) ? m[r] : 0ull;
  for (int g = 0; g < cnt; g += 16) {
#pragma unroll
    for (int r = 0; r < 16; r++) {
      int i = g + 16 + r;
      nxt[r] = (ld && i < cnt) ? m[i] : 0ull;
    }
#pragma unroll
    for (int r = 0; r < 16; r++) {
      int i = g + r;
      if (i < cnt) {
        u64 kw = __shfl(keepw, i >> 6);
        if ((kw >> (i & 63)) & 1ull) keepw &= ~cur[r];
      }
      cur[r] = nxt[r];
    }
  }
  if (lane < 16) keep_out[pair * 16 + lane] = keepw;
}

// ---------------------------------------------------------------------------
// kernel 5a: per pair: emit top-min(mb,kept) kept keys. 1 wave per pair.
// key = (score_bits << 32) | ~(c*KNMS + k)
// ---------------------------------------------------------------------------
__global__ __launch_bounds__(64) void k_fa(const u64* __restrict__ keepm,
    const float* __restrict__ scores_s, u64* __restrict__ fa, int C, int mb) {
  int pair = blockIdx.x;
  int lane = threadIdx.x;
  int c = pair % C;
  u64 kw = (lane < 16) ? keepm[pair * 16 + lane] : 0ull;
  int pc = __popcll(kw);
  int scan = pc;
  for (int d = 1; d < 16; d <<= 1) {
    int o = __shfl_up(scan, d);
    if (lane >= d) scan += o;
  }
  int base = scan - pc;
  int total = __shfl(scan, 15);
  if (lane < 16) {
    u64 m = kw; int r = base;
    while (m && r < mb) {
      int bit = __ffsll((long long)m) - 1; m &= m - 1;
      int k = lane * 64 + bit;
      float s = scores_s[(size_t)pair * KP + k];
      fa[(size_t)pair * mb + r] =
          ((u64)__float_as_uint(s) << 32) | (unsigned)(~(unsigned)(c * KNMS + k));
      r++;
    }
  }
  int start = total < mb ? total : mb;
  for (int r = start + lane; r < mb; r += 64) fa[(size_t)pair * mb + r] = 0ull;
}

// ---------------------------------------------------------------------------
// kernel 5b: per batch: top-mb of C*mb keys via 2-level radix select +
// 1024-key bitonic (round-7 version).
// ---------------------------------------------------------------------------
__global__ __launch_bounds__(1024) void k_fb(const u64* __restrict__ fa,
    const float* __restrict__ boxes_s, float* __restrict__ out,
    int B, int C, int mb) {
  int b = blockIdx.x, tid = threadIdx.x;
  __shared__ union { unsigned int hist[NBIN]; u64 cand[FSEL]; } sh;
  __shared__ unsigned int csum[1024];
  __shared__ unsigned int s_b1, s_gt, s_tot, s_b2, s_gt2, s_tot2;
  __shared__ int s_all, s_all2, s_n, s_lvl2;
  int nk = C * mb;
  const u64* src = fa + (size_t)b * nk;

  for (int i = tid; i < NBIN; i += 1024) sh.hist[i] = 0u;
  __syncthreads();
  for (int i = tid; i < nk; i += 1024) {
    u64 key = src[i];
    if (key) atomicAdd(&sh.hist[(unsigned)(key >> 32) >> 18], 1u);
  }
  __syncthreads();
  find_cutoff(sh.hist, NBIN, csum, 1024, tid, (unsigned)mb, &s_b1, &s_gt, &s_tot, &s_all);
  unsigned b1 = s_all ? 0u : s_b1;
  unsigned gt1 = s_gt, tot = s_tot;
  int all1 = s_all;
  unsigned m1 = sh.hist[b1];
  if (tid == 0) s_lvl2 = (!all1 && gt1 + m1 > FSEL) ? 1 : 0;
  __syncthreads();
  int lvl2 = s_lvl2;
  unsigned b2 = 0; int all2 = 1;
  if (lvl2) {
    for (int i = tid; i < 2048; i += 1024) sh.hist[i] = 0u;
    __syncthreads();
    for (int i = tid; i < nk; i += 1024) {
      u64 key = src[i];
      if (key) {
        unsigned bits = (unsigned)(key >> 32);
        if ((bits >> 18) == b1) atomicAdd(&sh.hist[(bits >> 7) & 2047u], 1u);
      }
    }
    __syncthreads();
    find_cutoff(sh.hist, 2048, csum, 1024, tid, (unsigned)mb - gt1,
                &s_b2, &s_gt2, &s_tot2, &s_all2);
    all2 = s_all2;
    b2 = all2 ? 0u : s_b2;
  }
  for (int t = tid; t < FSEL; t += 1024) sh.cand[t] = 0ull;
  if (tid == 0) s_n = 0;
  __syncthreads();
  for (int i = tid; i < nk; i += 1024) {
    u64 key = src[i];
    if (!key) continue;
    unsigned bits = (unsigned)(key >> 32);
    unsigned bin = bits >> 18;
    bool take = all1 || bin > b1 ||
                (bin == b1 && (!lvl2 || all2 || ((bits >> 7) & 2047u) >= b2));
    if (take) {
      int pos = atomicAdd(&s_n, 1);
      if (pos < FSEL) sh.cand[pos] = key;
    }
  }
  __syncthreads();
  bitonic_desc<FSEL, 1024>(sh.cand, tid);

  int n_out = (int)tot < mb ? (int)tot : mb;
  for (int k = tid; k < mb; k += 1024) {
    u64 key = sh.cand[k];
    float4 bx = make_float4(0.f, 0.f, 0.f, 0.f);
    float sc = 0.f, cf = -1.f;
    if (k < n_out && key != 0ull) {
      sc = __uint_as_float((unsigned)(key >> 32));
      unsigned flat = ~(unsigned)key;
      int c = flat / KNMS;
      int kk = flat - c * KNMS;
      bx = ((const float4*)boxes_s)[(size_t)(b * C + c) * KP + kk];
      cf = (float)c;
    }
    size_t ro = (size_t)(b * mb + k) * 4;
    out[ro + 0] = bx.x; out[ro + 1] = bx.y; out[ro + 2] = bx.z; out[ro + 3] = bx.w;
    out[(size_t)B * mb * 4 + b * mb + k] = sc;
    out[(size_t)B * mb * 5 + b * mb + k] = cf;
  }
}

// ---------------------------------------------------------------------------
extern "C" void kernel_launch(void* const* d_in, const int* in_sizes, int n_in,
                              void* d_out, int out_size, void* d_ws, size_t ws_size,
                              hipStream_t stream) {
  const float* classification = (const float*)d_in[3];
  const float* tanch = (const float*)d_in[4];
  const float* thr_p = (const float*)d_in[5];

  int B = in_sizes[0] / (3 * 64 * 64);
  if (B <= 0) B = 4;
  long long BA = (long long)in_sizes[4] / 4;
  int A = (int)(BA / B);
  int C = (int)((long long)in_sizes[3] / BA);
  int NP = B * C;
  int mb = out_size / (B * 6);

  auto rsz = [](size_t x) { return (x + 255) & ~(size_t)255; };
  size_t off = 0;
  auto take = [&](size_t bytes) {
    void* p = (char*)d_ws + off;
    off += rsz(bytes);
    return p;
  };
  float* scores_s = (float*)take((size_t)NP * KP * 4);
  float* boxes_s  = (float*)take((size_t)NP * KP * 16);
  float* area_s   = (float*)take((size_t)NP * KP * 4);
  int*   cnt_s    = (int*)take((size_t)NP * 4);
  u64*   mat      = (u64*)take((size_t)NP * KP * 16 * 8);  // 41.9 MB
  u64*   keepm    = (u64*)take((size_t)NP * 16 * 8);

  // Aliases inside the mat region (disjoint lifetimes):
  //   gcand/gpc/gcut/gflag live k_sample..k_selB (before k_iou writes mat);
  //   fa lives k_fa..k_fb (after k_scan's last read of mat).
  char* matc = (char*)mat;
  size_t ao = 0;
  u64* gcand      = (u64*)(matc + ao);      ao += rsz((size_t)NP * SLOTS * 8);   // 26.2 MB
  unsigned* gpc   = (unsigned*)(matc + ao); ao += rsz((size_t)NP * SLICES * 4);  // 0.41 MB
  unsigned* gcut  = (unsigned*)(matc + ao); ao += rsz((size_t)NP * 4);
  unsigned* gflag = (unsigned*)(matc + ao); ao += rsz((size_t)NP * 4);
  u64* fa = (u64*)mat;

  int fastsel = (C <= CMAX) ? 1 : 0;
  hipMemsetAsync(gflag, fastsel ? 0 : 1, (size_t)NP * 4, stream);

  if (fastsel) {
    k_sample<<<B, 1024, 0, stream>>>(classification, thr_p, gcut, A, C);
    k_selA<<<dim3(SLICES, B), 512, 0, stream>>>(classification, thr_p, gcut,
                                                gcand, gpc, gflag, A, C);
  } else {
    hipMemsetAsync(gcut, 0, (size_t)NP * 4, stream);
  }
  k_selB<<<NP, 1024, 0, stream>>>(gcand, gpc, gcut, gflag, classification, thr_p,
                                  tanch, scores_s, boxes_s, area_s, cnt_s, A, C);
  k_iou<<<dim3(NP, 16), 256, 0, stream>>>(boxes_s, area_s, cnt_s, mat);
  k_scan<<<NP, 64, 0, stream>>>(mat, cnt_s, keepm);
  k_fa<<<NP, 64, 0, stream>>>(keepm, scores_s, fa, C, mb);
  k_fb<<<B, 1024, 0, stream>>>(fa, boxes_s, (float*)d_out, B, C, mb);
}